// Round 2
// baseline (8837.372 us; speedup 1.0000x reference)
//
#include <hip/hip_runtime.h>

// Problem constants (reference: T=64 time steps, B=SEQ=128 batch, IN=256, H=512)
#define TT 64
#define BB 128
#define IND 256
#define HH 512
#define GG 2048      // 4*H
#define NCC 10
#define KFLAT 65536  // SEQ*H
#define HPAD 132     // 128-col chunk + 4 pad floats (16B-aligned rows, 2-way banks max)

// ---------------------------------------------------------------------------
// GEMM: C[m,n] = sum_k A[m,k]*W[n,k] + b0[n] + b1[n]   (unchanged from R1)
// ---------------------------------------------------------------------------
__global__ __launch_bounds__(256) void gemm_bias_kernel(
    const float* __restrict__ A, const float* __restrict__ W,
    const float* __restrict__ b0, const float* __restrict__ b1,
    float* __restrict__ C, int K, int N)
{
    const int m0 = blockIdx.x * 64;
    const int n0 = blockIdx.y * 64;
    const int tid = threadIdx.x;
    __shared__ float As[32][68];
    __shared__ float Bs[32][68];
    const int tm = tid >> 4;
    const int tn = tid & 15;
    float acc[4][4] = {};

    for (int kt = 0; kt < K; kt += 32) {
        #pragma unroll
        for (int q = tid; q < 512; q += 256) {
            const int mm = q >> 3;
            const int kq = q & 7;
            float4 v = *(const float4*)&A[(size_t)(m0 + mm) * K + kt + kq * 4];
            As[kq*4+0][mm] = v.x; As[kq*4+1][mm] = v.y;
            As[kq*4+2][mm] = v.z; As[kq*4+3][mm] = v.w;
            float4 w = *(const float4*)&W[(size_t)(n0 + mm) * K + kt + kq * 4];
            Bs[kq*4+0][mm] = w.x; Bs[kq*4+1][mm] = w.y;
            Bs[kq*4+2][mm] = w.z; Bs[kq*4+3][mm] = w.w;
        }
        __syncthreads();
        #pragma unroll
        for (int k = 0; k < 32; ++k) {
            float4 a = *(const float4*)&As[k][tm * 4];
            float4 b = *(const float4*)&Bs[k][tn * 4];
            acc[0][0] += a.x*b.x; acc[0][1] += a.x*b.y; acc[0][2] += a.x*b.z; acc[0][3] += a.x*b.w;
            acc[1][0] += a.y*b.x; acc[1][1] += a.y*b.y; acc[1][2] += a.y*b.z; acc[1][3] += a.y*b.w;
            acc[2][0] += a.z*b.x; acc[2][1] += a.z*b.y; acc[2][2] += a.z*b.z; acc[2][3] += a.z*b.w;
            acc[3][0] += a.w*b.x; acc[3][1] += a.w*b.y; acc[3][2] += a.w*b.z; acc[3][3] += a.w*b.w;
        }
        __syncthreads();
    }
    #pragma unroll
    for (int i = 0; i < 4; ++i) {
        const int m = m0 + tm * 4 + i;
        #pragma unroll
        for (int j = 0; j < 4; ++j) {
            const int n = n0 + tn * 4 + j;
            C[(size_t)m * N + n] = acc[i][j] + b0[n] + b1[n];
        }
    }
}

// ---------------------------------------------------------------------------
// Device-scope grid barrier (generation counting). bar[0]=counter, bar[1]=gen.
// Grid must be fully co-resident: grid=256 WGs, 37.9KB LDS -> >=4 WG/CU
// capacity -> all resident under any packing. Same construction as ROCm CG.
// ---------------------------------------------------------------------------
__device__ __forceinline__ void grid_barrier(unsigned* bar, unsigned target)
{
    __threadfence();          // release h stores device-wide (agent scope)
    __syncthreads();
    if (threadIdx.x == 0) {
        unsigned prev = __hip_atomic_fetch_add(&bar[0], 1u, __ATOMIC_ACQ_REL,
                                               __HIP_MEMORY_SCOPE_AGENT);
        if (prev == 255u) {
            __hip_atomic_store(&bar[0], 0u, __ATOMIC_RELAXED, __HIP_MEMORY_SCOPE_AGENT);
            __hip_atomic_store(&bar[1], target, __ATOMIC_RELEASE, __HIP_MEMORY_SCOPE_AGENT);
        } else {
            while (__hip_atomic_load(&bar[1], __ATOMIC_ACQUIRE,
                                     __HIP_MEMORY_SCOPE_AGENT) < target) {
                __builtin_amdgcn_s_sleep(2);
            }
        }
        __threadfence();      // acquire: invalidate stale L1/L2 before h(t) reads
    }
    __syncthreads();
}

// ---------------------------------------------------------------------------
// Persistent LSTM layer. Grid = 256 WGs x 256 thr. WG (bt,gt) owns
// batches [bt*32, +32) x hidden units [gt*8, +8) x 4 gates.
// Per step: stage h(t) 32x512 + W_hh 32 rows into LDS (4 k-chunks of 128),
// each thread computes 4 dot products (2 batches x 2 gates), exchange via
// LDS, c/h elementwise in registers, write h(t+1), grid barrier.
// hseq has a zeroed block at t=0; writes go to block t+1.
// ---------------------------------------------------------------------------
__global__ __launch_bounds__(256) void lstm_persistent(
    const float* __restrict__ xg,    // [T][B][4H] (biases already added)
    const float* __restrict__ w_hh,  // [4H][H]
    float* __restrict__ hseq,        // [T+1][B][H], block 0 zeroed
    unsigned* __restrict__ bar)
{
    __shared__ float Hs[32][HPAD];
    __shared__ float Ws[32][HPAD];
    __shared__ float Gs[8][4][32];   // [j][gate][b]

    const int tid = threadIdx.x;
    const int bt  = blockIdx.x & 3;
    const int j0  = (blockIdx.x >> 2) * 8;

    // mainloop roles: cells (b in {b2,b2+16}) x (gates {2g2,2g2+1}) x j_l
    const int b2  = tid & 15;
    const int g2  = (tid >> 4) & 1;
    const int j_l = tid >> 5;        // 0..7
    const int r0  = 16 * g2 + j_l;   // Ws row of gate 2g2, unit j_l
    const int r1  = r0 + 8;          // gate 2g2+1
    // staging roles: q = tid: col4 = q&31 (float4 col), rows rr0 + 8p
    const int col4 = tid & 31;
    const int rr0  = tid >> 5;
    // update roles: one (b_u, j_u) cell
    const int b_u = tid & 31;
    const int j_u = tid >> 5;

    float c_reg = 0.f;

    for (int t = 0; t < TT; ++t) {
        const float* hsrc = hseq + (size_t)t * (BB * HH) + (size_t)bt * 32 * HH;
        float acc00 = 0.f, acc01 = 0.f, acc10 = 0.f, acc11 = 0.f;

        for (int kc = 0; kc < 4; ++kc) {
            // ---- stage h-chunk and W-chunk (coalesced 16B lanes) ----
            #pragma unroll
            for (int p = 0; p < 4; ++p) {
                const int rr = rr0 + p * 8;
                float4 hv = *(const float4*)&hsrc[(size_t)rr * HH + kc * 128 + col4 * 4];
                *(float4*)&Hs[rr][col4 * 4] = hv;
                const int g = rr >> 3, jj = rr & 7;
                float4 wv = *(const float4*)&w_hh[(size_t)(g * HH + j0 + jj) * HH + kc * 128 + col4 * 4];
                *(float4*)&Ws[rr][col4 * 4] = wv;
            }
            __syncthreads();
            // ---- 32 k4 rounds: 4 ds_read_b128 + 16 FMA ----
            #pragma unroll 4
            for (int k4 = 0; k4 < 32; ++k4) {
                float4 h0v = *(const float4*)&Hs[b2][k4 * 4];
                float4 h1v = *(const float4*)&Hs[b2 + 16][k4 * 4];
                float4 w0v = *(const float4*)&Ws[r0][k4 * 4];
                float4 w1v = *(const float4*)&Ws[r1][k4 * 4];
                acc00 += h0v.x*w0v.x + h0v.y*w0v.y + h0v.z*w0v.z + h0v.w*w0v.w;
                acc01 += h0v.x*w1v.x + h0v.y*w1v.y + h0v.z*w1v.z + h0v.w*w1v.w;
                acc10 += h1v.x*w0v.x + h1v.y*w0v.y + h1v.z*w0v.z + h1v.w*w0v.w;
                acc11 += h1v.x*w1v.x + h1v.y*w1v.y + h1v.z*w1v.z + h1v.w*w1v.w;
            }
            __syncthreads();
        }

        // ---- exchange gate pre-activations ----
        Gs[j_l][2*g2+0][b2]      = acc00;
        Gs[j_l][2*g2+1][b2]      = acc01;
        Gs[j_l][2*g2+0][b2 + 16] = acc10;
        Gs[j_l][2*g2+1][b2 + 16] = acc11;
        __syncthreads();

        // ---- elementwise update for this thread's (b_u, j_u) cell ----
        {
            const int b = bt * 32 + b_u;
            const float* xt = xg + (size_t)t * (BB * GG) + (size_t)b * GG + j0 + j_u;
            const float gi = Gs[j_u][0][b_u] + xt[0];
            const float gf = Gs[j_u][1][b_u] + xt[HH];
            const float gg = Gs[j_u][2][b_u] + xt[2 * HH];
            const float go = Gs[j_u][3][b_u] + xt[3 * HH];
            const float si = 1.f / (1.f + __expf(-gi));
            const float sf = 1.f / (1.f + __expf(-gf));
            const float tg = 2.f / (1.f + __expf(-2.f * gg)) - 1.f;
            const float so = 1.f / (1.f + __expf(-go));
            c_reg = sf * c_reg + si * tg;
            const float th = 2.f / (1.f + __expf(-2.f * c_reg)) - 1.f;
            hseq[(size_t)(t + 1) * (BB * HH) + (size_t)b * HH + j0 + j_u] = so * th;
        }
        __syncthreads();   // protect Gs before next step's reuse

        if (t != TT - 1) grid_barrier(bar, (unsigned)(t + 1));
    }
}

// ---------------------------------------------------------------------------
// Classifier split-K partial GEMM (unchanged from R1)
// ---------------------------------------------------------------------------
__global__ __launch_bounds__(256) void cls_partial_kernel(
    const float* __restrict__ A, const float* __restrict__ W,
    float* __restrict__ part)
{
    const int n0 = blockIdx.x * 64;
    const int s  = blockIdx.y;
    const int kbase = s * 2048;
    const int tid = threadIdx.x;
    __shared__ float As[32][68];
    __shared__ float Bs[32][68];
    const int tm = tid >> 4, tn = tid & 15;
    float acc[4][4] = {};

    for (int kt = 0; kt < 2048; kt += 32) {
        #pragma unroll
        for (int q = tid; q < 512; q += 256) {
            const int mm = q >> 3;
            const int kq = q & 7;
            float4 v = *(const float4*)&A[(size_t)mm * KFLAT + kbase + kt + kq * 4];
            As[kq*4+0][mm] = v.x; As[kq*4+1][mm] = v.y;
            As[kq*4+2][mm] = v.z; As[kq*4+3][mm] = v.w;
            float4 w = *(const float4*)&W[(size_t)(n0 + mm) * KFLAT + kbase + kt + kq * 4];
            Bs[kq*4+0][mm] = w.x; Bs[kq*4+1][mm] = w.y;
            Bs[kq*4+2][mm] = w.z; Bs[kq*4+3][mm] = w.w;
        }
        __syncthreads();
        #pragma unroll
        for (int k = 0; k < 32; ++k) {
            float4 a = *(const float4*)&As[k][tm * 4];
            float4 b = *(const float4*)&Bs[k][tn * 4];
            acc[0][0] += a.x*b.x; acc[0][1] += a.x*b.y; acc[0][2] += a.x*b.z; acc[0][3] += a.x*b.w;
            acc[1][0] += a.y*b.x; acc[1][1] += a.y*b.y; acc[1][2] += a.y*b.z; acc[1][3] += a.y*b.w;
            acc[2][0] += a.z*b.x; acc[2][1] += a.z*b.y; acc[2][2] += a.z*b.z; acc[2][3] += a.z*b.w;
            acc[3][0] += a.w*b.x; acc[3][1] += a.w*b.y; acc[3][2] += a.w*b.z; acc[3][3] += a.w*b.w;
        }
        __syncthreads();
    }
    #pragma unroll
    for (int i = 0; i < 4; ++i) {
        const int m = tm * 4 + i;
        #pragma unroll
        for (int j = 0; j < 4; ++j) {
            part[((size_t)s * 64 + m) * 512 + n0 + tn * 4 + j] = acc[i][j];
        }
    }
}

// ---------------------------------------------------------------------------
// Classifier finish (unchanged from R1)
// ---------------------------------------------------------------------------
__global__ __launch_bounds__(256) void cls_final_kernel(
    const float* __restrict__ part, const float* __restrict__ b1,
    const float* __restrict__ w2, const float* __restrict__ b2,
    float* __restrict__ out)
{
    const int t = blockIdx.x;
    __shared__ float hm[512];
    for (int n = threadIdx.x; n < 512; n += 256) {
        float sacc = b1[n];
        for (int sl = 0; sl < 32; ++sl)
            sacc += part[((size_t)sl * 64 + t) * 512 + n];
        hm[n] = fmaxf(sacc, 0.f);
    }
    __syncthreads();
    if (threadIdx.x < NCC) {
        float sacc = b2[threadIdx.x];
        const float* wr = w2 + (size_t)threadIdx.x * 512;
        for (int n = 0; n < 512; ++n) sacc += hm[n] * wr[n];
        out[t * NCC + threadIdx.x] = sacc;
    }
}

// ---------------------------------------------------------------------------
extern "C" void kernel_launch(void* const* d_in, const int* in_sizes, int n_in,
                              void* d_out, int out_size, void* d_ws, size_t ws_size,
                              hipStream_t stream)
{
    const float* x     = (const float*)d_in[0];
    const float* w_ih0 = (const float*)d_in[1];
    const float* w_hh0 = (const float*)d_in[2];
    const float* b_ih0 = (const float*)d_in[3];
    const float* b_hh0 = (const float*)d_in[4];
    const float* w_ih1 = (const float*)d_in[5];
    const float* w_hh1 = (const float*)d_in[6];
    const float* b_ih1 = (const float*)d_in[7];
    const float* b_hh1 = (const float*)d_in[8];
    const float* w1    = (const float*)d_in[9];
    const float* b1    = (const float*)d_in[10];
    const float* w2    = (const float*)d_in[11];
    const float* b2    = (const float*)d_in[12];
    float* out = (float*)d_out;

    // Workspace layout (floats)
    float* ws    = (float*)d_ws;
    float* xg    = ws;                            // [8192,2048]   = 16,777,216
    float* hseq0 = xg + (size_t)8192 * 2048;      // [65][128][512]=  4,259,840
    float* hseq1 = hseq0 + (size_t)65 * BB * HH;  // [65][128][512]=  4,259,840
    float* part  = hseq1 + (size_t)65 * BB * HH;  // [32][64][512] =  1,048,576
    unsigned* bar = (unsigned*)(part + (size_t)32 * 64 * 512);  // 2 uints

    // zero the t=0 h blocks and barrier state
    hipMemsetAsync(hseq0, 0, (size_t)BB * HH * sizeof(float), stream);
    hipMemsetAsync(hseq1, 0, (size_t)BB * HH * sizeof(float), stream);
    hipMemsetAsync(bar, 0, 2 * sizeof(unsigned), stream);

    // ---- layer 0 ----
    gemm_bias_kernel<<<dim3(8192 / 64, GG / 64), 256, 0, stream>>>(
        x, w_ih0, b_ih0, b_hh0, xg, IND, GG);
    lstm_persistent<<<256, 256, 0, stream>>>(xg, w_hh0, hseq0, bar);

    // ---- layer 1 ----
    gemm_bias_kernel<<<dim3(8192 / 64, GG / 64), 256, 0, stream>>>(
        hseq0 + (size_t)BB * HH, w_ih1, b_ih1, b_hh1, xg, HH, GG);
    hipMemsetAsync(bar, 0, 2 * sizeof(unsigned), stream);
    lstm_persistent<<<256, 256, 0, stream>>>(xg, w_hh1, hseq1, bar);

    // ---- classifier ----
    cls_partial_kernel<<<dim3(512 / 64, 32), 256, 0, stream>>>(
        hseq1 + (size_t)BB * HH, w1, part);
    cls_final_kernel<<<64, 256, 0, stream>>>(part, b1, w2, b2, out);
}

// Round 3
// 3352.707 us; speedup vs baseline: 2.6359x; 2.6359x over previous
//
#include <hip/hip_runtime.h>

// Problem constants (reference: T=64 time steps, B=SEQ=128 batch, IN=256, H=512)
#define TT 64
#define BB 128
#define IND 256
#define HH 512
#define GG 2048      // 4*H
#define NCC 10
#define KFLAT 65536  // SEQ*H
#define HPAD 132     // 128-col chunk + 4 pad floats

// ---------------------------------------------------------------------------
// GEMM: C[m,n] = sum_k A[m,k]*W[n,k] + b0[n] + b1[n]   (unchanged)
// ---------------------------------------------------------------------------
__global__ __launch_bounds__(256) void gemm_bias_kernel(
    const float* __restrict__ A, const float* __restrict__ W,
    const float* __restrict__ b0, const float* __restrict__ b1,
    float* __restrict__ C, int K, int N)
{
    const int m0 = blockIdx.x * 64;
    const int n0 = blockIdx.y * 64;
    const int tid = threadIdx.x;
    __shared__ float As[32][68];
    __shared__ float Bs[32][68];
    const int tm = tid >> 4;
    const int tn = tid & 15;
    float acc[4][4] = {};

    for (int kt = 0; kt < K; kt += 32) {
        #pragma unroll
        for (int q = tid; q < 512; q += 256) {
            const int mm = q >> 3;
            const int kq = q & 7;
            float4 v = *(const float4*)&A[(size_t)(m0 + mm) * K + kt + kq * 4];
            As[kq*4+0][mm] = v.x; As[kq*4+1][mm] = v.y;
            As[kq*4+2][mm] = v.z; As[kq*4+3][mm] = v.w;
            float4 w = *(const float4*)&W[(size_t)(n0 + mm) * K + kt + kq * 4];
            Bs[kq*4+0][mm] = w.x; Bs[kq*4+1][mm] = w.y;
            Bs[kq*4+2][mm] = w.z; Bs[kq*4+3][mm] = w.w;
        }
        __syncthreads();
        #pragma unroll
        for (int k = 0; k < 32; ++k) {
            float4 a = *(const float4*)&As[k][tm * 4];
            float4 b = *(const float4*)&Bs[k][tn * 4];
            acc[0][0] += a.x*b.x; acc[0][1] += a.x*b.y; acc[0][2] += a.x*b.z; acc[0][3] += a.x*b.w;
            acc[1][0] += a.y*b.x; acc[1][1] += a.y*b.y; acc[1][2] += a.y*b.z; acc[1][3] += a.y*b.w;
            acc[2][0] += a.z*b.x; acc[2][1] += a.z*b.y; acc[2][2] += a.z*b.z; acc[2][3] += a.z*b.w;
            acc[3][0] += a.w*b.x; acc[3][1] += a.w*b.y; acc[3][2] += a.w*b.z; acc[3][3] += a.w*b.w;
        }
        __syncthreads();
    }
    #pragma unroll
    for (int i = 0; i < 4; ++i) {
        const int m = m0 + tm * 4 + i;
        #pragma unroll
        for (int j = 0; j < 4; ++j) {
            const int n = n0 + tn * 4 + j;
            C[(size_t)m * N + n] = acc[i][j] + b0[n] + b1[n];
        }
    }
}

// ---------------------------------------------------------------------------
// Fence-free grid barrier. bar[0] = monotonic arrival counter (never reset),
// bar[1] = published generation. All atomics RELAXED agent scope (sc1 ops to
// the coherent IF$ point -> NO L2 invalidates). Store drain comes from the
// s_waitcnt vmcnt(0) the compiler emits before s_barrier (__syncthreads).
// 256 WGs, 37.9KB LDS -> >=4 WG/CU capacity -> full co-residency guaranteed.
// ---------------------------------------------------------------------------
__device__ __forceinline__ void grid_barrier(unsigned* bar, unsigned gen)
{
    __syncthreads();   // drains this WG's h atomic stores (vmcnt(0) before s_barrier)
    if (threadIdx.x == 0) {
        unsigned prev = __hip_atomic_fetch_add(&bar[0], 1u, __ATOMIC_RELAXED,
                                               __HIP_MEMORY_SCOPE_AGENT);
        if (prev == gen * 256u - 1u) {
            __hip_atomic_store(&bar[1], gen, __ATOMIC_RELAXED,
                               __HIP_MEMORY_SCOPE_AGENT);
        } else {
            while (__hip_atomic_load(&bar[1], __ATOMIC_RELAXED,
                                     __HIP_MEMORY_SCOPE_AGENT) < gen) {
                __builtin_amdgcn_s_sleep(2);
            }
        }
    }
    __syncthreads();
    asm volatile("" ::: "memory");   // no compiler reordering across the barrier
}

// ---------------------------------------------------------------------------
// Persistent LSTM layer. Grid = 256 WGs x 256 thr. WG (bt,j0) owns
// batches [bt*32,+32) x hidden units [j0,+8) x 4 gates.
// h is exchanged through IF$ via relaxed agent atomics (8B loads / 4B stores);
// xg and W_hh are read-only and stay L2-cached (never invalidated).
// ---------------------------------------------------------------------------
__global__ __launch_bounds__(256) void lstm_persistent(
    const float* __restrict__ xg,    // [T][B][4H] (biases already added)
    const float* __restrict__ w_hh,  // [4H][H]
    float* __restrict__ hseq,        // [T+1][B][H], block 0 zeroed
    unsigned* __restrict__ bar)
{
    __shared__ float Hs[32][HPAD];
    __shared__ float Ws[32][HPAD];
    __shared__ float Gs[8][4][32];   // [j][gate][b]

    const int tid = threadIdx.x;
    const int bt  = blockIdx.x & 3;
    const int j0  = (blockIdx.x >> 2) * 8;

    // mainloop roles
    const int b2  = tid & 15;
    const int g2  = (tid >> 4) & 1;
    const int j_l = tid >> 5;        // 0..7
    const int r0  = 16 * g2 + j_l;
    const int r1  = r0 + 8;
    // h staging roles: 8B columns
    const int col2 = tid & 63;       // 0..63 (x2 float col)
    const int rr8  = tid >> 6;       // 0..3
    // W staging roles: 16B columns
    const int col4 = tid & 31;
    const int rr0  = tid >> 5;       // 0..7
    // update roles
    const int b_u = tid & 31;
    const int j_u = tid >> 5;

    float c_reg = 0.f;

    for (int t = 0; t < TT; ++t) {
        const float* hsrc = hseq + (size_t)t * (BB * HH) + (size_t)bt * 32 * HH;
        float acc00 = 0.f, acc01 = 0.f, acc10 = 0.f, acc11 = 0.f;

        for (int kc = 0; kc < 4; ++kc) {
            // ---- stage h-chunk via coherent 8B atomic loads ----
            #pragma unroll
            for (int p = 0; p < 8; ++p) {
                const int rr = rr8 + p * 4;
                unsigned long long raw = __hip_atomic_load(
                    (const unsigned long long*)&hsrc[(size_t)rr * HH + kc * 128 + col2 * 2],
                    __ATOMIC_RELAXED, __HIP_MEMORY_SCOPE_AGENT);
                *(float2*)&Hs[rr][col2 * 2] = __builtin_bit_cast(float2, raw);
            }
            // ---- stage W-chunk (normal cached float4 loads) ----
            #pragma unroll
            for (int p = 0; p < 4; ++p) {
                const int rr = rr0 + p * 8;
                const int g = rr >> 3, jj = rr & 7;
                float4 wv = *(const float4*)&w_hh[(size_t)(g * HH + j0 + jj) * HH + kc * 128 + col4 * 4];
                *(float4*)&Ws[rr][col4 * 4] = wv;
            }
            __syncthreads();
            // ---- 32 k4 rounds: 4 ds_read_b128 + 16 FMA ----
            #pragma unroll 4
            for (int k4 = 0; k4 < 32; ++k4) {
                float4 h0v = *(const float4*)&Hs[b2][k4 * 4];
                float4 h1v = *(const float4*)&Hs[b2 + 16][k4 * 4];
                float4 w0v = *(const float4*)&Ws[r0][k4 * 4];
                float4 w1v = *(const float4*)&Ws[r1][k4 * 4];
                acc00 += h0v.x*w0v.x + h0v.y*w0v.y + h0v.z*w0v.z + h0v.w*w0v.w;
                acc01 += h0v.x*w1v.x + h0v.y*w1v.y + h0v.z*w1v.z + h0v.w*w1v.w;
                acc10 += h1v.x*w0v.x + h1v.y*w0v.y + h1v.z*w0v.z + h1v.w*w0v.w;
                acc11 += h1v.x*w1v.x + h1v.y*w1v.y + h1v.z*w1v.z + h1v.w*w1v.w;
            }
            __syncthreads();
        }

        // ---- exchange gate pre-activations ----
        Gs[j_l][2*g2+0][b2]      = acc00;
        Gs[j_l][2*g2+1][b2]      = acc01;
        Gs[j_l][2*g2+0][b2 + 16] = acc10;
        Gs[j_l][2*g2+1][b2 + 16] = acc11;
        __syncthreads();

        // ---- elementwise update; h written via coherent atomic store ----
        {
            const int b = bt * 32 + b_u;
            const float* xt = xg + (size_t)t * (BB * GG) + (size_t)b * GG + j0 + j_u;
            const float gi = Gs[j_u][0][b_u] + xt[0];
            const float gf = Gs[j_u][1][b_u] + xt[HH];
            const float gg = Gs[j_u][2][b_u] + xt[2 * HH];
            const float go = Gs[j_u][3][b_u] + xt[3 * HH];
            const float si = 1.f / (1.f + __expf(-gi));
            const float sf = 1.f / (1.f + __expf(-gf));
            const float tg = 2.f / (1.f + __expf(-2.f * gg)) - 1.f;
            const float so = 1.f / (1.f + __expf(-go));
            c_reg = sf * c_reg + si * tg;
            const float th = 2.f / (1.f + __expf(-2.f * c_reg)) - 1.f;
            __hip_atomic_store(
                &hseq[(size_t)(t + 1) * (BB * HH) + (size_t)b * HH + j0 + j_u],
                so * th, __ATOMIC_RELAXED, __HIP_MEMORY_SCOPE_AGENT);
        }
        __syncthreads();   // protect Gs before next step reuses it

        if (t != TT - 1) grid_barrier(bar, (unsigned)(t + 1));
    }
}

// ---------------------------------------------------------------------------
// Classifier split-K partial GEMM (unchanged)
// ---------------------------------------------------------------------------
__global__ __launch_bounds__(256) void cls_partial_kernel(
    const float* __restrict__ A, const float* __restrict__ W,
    float* __restrict__ part)
{
    const int n0 = blockIdx.x * 64;
    const int s  = blockIdx.y;
    const int kbase = s * 2048;
    const int tid = threadIdx.x;
    __shared__ float As[32][68];
    __shared__ float Bs[32][68];
    const int tm = tid >> 4, tn = tid & 15;
    float acc[4][4] = {};

    for (int kt = 0; kt < 2048; kt += 32) {
        #pragma unroll
        for (int q = tid; q < 512; q += 256) {
            const int mm = q >> 3;
            const int kq = q & 7;
            float4 v = *(const float4*)&A[(size_t)mm * KFLAT + kbase + kt + kq * 4];
            As[kq*4+0][mm] = v.x; As[kq*4+1][mm] = v.y;
            As[kq*4+2][mm] = v.z; As[kq*4+3][mm] = v.w;
            float4 w = *(const float4*)&W[(size_t)(n0 + mm) * KFLAT + kbase + kt + kq * 4];
            Bs[kq*4+0][mm] = w.x; Bs[kq*4+1][mm] = w.y;
            Bs[kq*4+2][mm] = w.z; Bs[kq*4+3][mm] = w.w;
        }
        __syncthreads();
        #pragma unroll
        for (int k = 0; k < 32; ++k) {
            float4 a = *(const float4*)&As[k][tm * 4];
            float4 b = *(const float4*)&Bs[k][tn * 4];
            acc[0][0] += a.x*b.x; acc[0][1] += a.x*b.y; acc[0][2] += a.x*b.z; acc[0][3] += a.x*b.w;
            acc[1][0] += a.y*b.x; acc[1][1] += a.y*b.y; acc[1][2] += a.y*b.z; acc[1][3] += a.y*b.w;
            acc[2][0] += a.z*b.x; acc[2][1] += a.z*b.y; acc[2][2] += a.z*b.z; acc[2][3] += a.z*b.w;
            acc[3][0] += a.w*b.x; acc[3][1] += a.w*b.y; acc[3][2] += a.w*b.z; acc[3][3] += a.w*b.w;
        }
        __syncthreads();
    }
    #pragma unroll
    for (int i = 0; i < 4; ++i) {
        const int m = tm * 4 + i;
        #pragma unroll
        for (int j = 0; j < 4; ++j) {
            part[((size_t)s * 64 + m) * 512 + n0 + tn * 4 + j] = acc[i][j];
        }
    }
}

// ---------------------------------------------------------------------------
// Classifier finish (unchanged)
// ---------------------------------------------------------------------------
__global__ __launch_bounds__(256) void cls_final_kernel(
    const float* __restrict__ part, const float* __restrict__ b1,
    const float* __restrict__ w2, const float* __restrict__ b2,
    float* __restrict__ out)
{
    const int t = blockIdx.x;
    __shared__ float hm[512];
    for (int n = threadIdx.x; n < 512; n += 256) {
        float sacc = b1[n];
        for (int sl = 0; sl < 32; ++sl)
            sacc += part[((size_t)sl * 64 + t) * 512 + n];
        hm[n] = fmaxf(sacc, 0.f);
    }
    __syncthreads();
    if (threadIdx.x < NCC) {
        float sacc = b2[threadIdx.x];
        const float* wr = w2 + (size_t)threadIdx.x * 512;
        for (int n = 0; n < 512; ++n) sacc += hm[n] * wr[n];
        out[t * NCC + threadIdx.x] = sacc;
    }
}

// ---------------------------------------------------------------------------
extern "C" void kernel_launch(void* const* d_in, const int* in_sizes, int n_in,
                              void* d_out, int out_size, void* d_ws, size_t ws_size,
                              hipStream_t stream)
{
    const float* x     = (const float*)d_in[0];
    const float* w_ih0 = (const float*)d_in[1];
    const float* w_hh0 = (const float*)d_in[2];
    const float* b_ih0 = (const float*)d_in[3];
    const float* b_hh0 = (const float*)d_in[4];
    const float* w_ih1 = (const float*)d_in[5];
    const float* w_hh1 = (const float*)d_in[6];
    const float* b_ih1 = (const float*)d_in[7];
    const float* b_hh1 = (const float*)d_in[8];
    const float* w1    = (const float*)d_in[9];
    const float* b1    = (const float*)d_in[10];
    const float* w2    = (const float*)d_in[11];
    const float* b2    = (const float*)d_in[12];
    float* out = (float*)d_out;

    // Workspace layout (floats)
    float* ws    = (float*)d_ws;
    float* xg    = ws;                            // [8192,2048]   = 16,777,216
    float* hseq0 = xg + (size_t)8192 * 2048;      // [65][128][512]=  4,259,840
    float* hseq1 = hseq0 + (size_t)65 * BB * HH;  // [65][128][512]=  4,259,840
    float* part  = hseq1 + (size_t)65 * BB * HH;  // [32][64][512] =  1,048,576
    unsigned* bar = (unsigned*)(part + (size_t)32 * 64 * 512);  // 2 uints

    hipMemsetAsync(hseq0, 0, (size_t)BB * HH * sizeof(float), stream);
    hipMemsetAsync(hseq1, 0, (size_t)BB * HH * sizeof(float), stream);
    hipMemsetAsync(bar, 0, 2 * sizeof(unsigned), stream);

    // ---- layer 0 ----
    gemm_bias_kernel<<<dim3(8192 / 64, GG / 64), 256, 0, stream>>>(
        x, w_ih0, b_ih0, b_hh0, xg, IND, GG);
    lstm_persistent<<<256, 256, 0, stream>>>(xg, w_hh0, hseq0, bar);

    // ---- layer 1 ----
    gemm_bias_kernel<<<dim3(8192 / 64, GG / 64), 256, 0, stream>>>(
        hseq0 + (size_t)BB * HH, w_ih1, b_ih1, b_hh1, xg, HH, GG);
    hipMemsetAsync(bar, 0, 2 * sizeof(unsigned), stream);
    lstm_persistent<<<256, 256, 0, stream>>>(xg, w_hh1, hseq1, bar);

    // ---- classifier ----
    cls_partial_kernel<<<dim3(512 / 64, 32), 256, 0, stream>>>(
        hseq1 + (size_t)BB * HH, w1, part);
    cls_final_kernel<<<64, 256, 0, stream>>>(part, b1, w2, b2, out);
}

// Round 4
// 2118.669 us; speedup vs baseline: 4.1712x; 1.5825x over previous
//
#include <hip/hip_runtime.h>

// Problem constants (reference: T=64 time steps, B=SEQ=128 batch, IN=256, H=512)
#define TT 64
#define BB 128
#define IND 256
#define HH 512
#define GG 2048      // 4*H
#define NCC 10
#define KFLAT 65536  // SEQ*H
#define HP2 520      // bf16 LDS row stride (512 + 8): 4-bank shift/row -> conflict-free b128

typedef __attribute__((ext_vector_type(8))) short bf16x8;   // 8 bf16 in 4 VGPRs
typedef __attribute__((ext_vector_type(4))) float floatx4;  // MFMA accumulator

__device__ __forceinline__ unsigned short f2bf(float x) {   // RNE round to bf16
    unsigned u = __builtin_bit_cast(unsigned, x);
    u += 0x7fffu + ((u >> 16) & 1u);
    return (unsigned short)(u >> 16);
}
__device__ __forceinline__ float bf2f(unsigned short h) {
    unsigned u = ((unsigned)h) << 16;
    return __builtin_bit_cast(float, u);
}

// ---------------------------------------------------------------------------
// GEMM: C[m,n] = sum_k A[m,k]*W[n,k] + b0[n] + b1[n]   (unchanged; R5 target)
// ---------------------------------------------------------------------------
__global__ __launch_bounds__(256) void gemm_bias_kernel(
    const float* __restrict__ A, const float* __restrict__ W,
    const float* __restrict__ b0, const float* __restrict__ b1,
    float* __restrict__ C, int K, int N)
{
    const int m0 = blockIdx.x * 64;
    const int n0 = blockIdx.y * 64;
    const int tid = threadIdx.x;
    __shared__ float As[32][68];
    __shared__ float Bs[32][68];
    const int tm = tid >> 4;
    const int tn = tid & 15;
    float acc[4][4] = {};

    for (int kt = 0; kt < K; kt += 32) {
        #pragma unroll
        for (int q = tid; q < 512; q += 256) {
            const int mm = q >> 3;
            const int kq = q & 7;
            float4 v = *(const float4*)&A[(size_t)(m0 + mm) * K + kt + kq * 4];
            As[kq*4+0][mm] = v.x; As[kq*4+1][mm] = v.y;
            As[kq*4+2][mm] = v.z; As[kq*4+3][mm] = v.w;
            float4 w = *(const float4*)&W[(size_t)(n0 + mm) * K + kt + kq * 4];
            Bs[kq*4+0][mm] = w.x; Bs[kq*4+1][mm] = w.y;
            Bs[kq*4+2][mm] = w.z; Bs[kq*4+3][mm] = w.w;
        }
        __syncthreads();
        #pragma unroll
        for (int k = 0; k < 32; ++k) {
            float4 a = *(const float4*)&As[k][tm * 4];
            float4 b = *(const float4*)&Bs[k][tn * 4];
            acc[0][0] += a.x*b.x; acc[0][1] += a.x*b.y; acc[0][2] += a.x*b.z; acc[0][3] += a.x*b.w;
            acc[1][0] += a.y*b.x; acc[1][1] += a.y*b.y; acc[1][2] += a.y*b.z; acc[1][3] += a.y*b.w;
            acc[2][0] += a.z*b.x; acc[2][1] += a.z*b.y; acc[2][2] += a.z*b.z; acc[2][3] += a.z*b.w;
            acc[3][0] += a.w*b.x; acc[3][1] += a.w*b.y; acc[3][2] += a.w*b.z; acc[3][3] += a.w*b.w;
        }
        __syncthreads();
    }
    #pragma unroll
    for (int i = 0; i < 4; ++i) {
        const int m = m0 + tm * 4 + i;
        #pragma unroll
        for (int j = 0; j < 4; ++j) {
            const int n = n0 + tn * 4 + j;
            C[(size_t)m * N + n] = acc[i][j] + b0[n] + b1[n];
        }
    }
}

// ---------------------------------------------------------------------------
// Fence-free grid barrier (proven in R3). Monotonic counter, relaxed agent
// atomics -> no L2 invalidates. 256 WGs, <=71KB LDS -> co-residency holds.
// ---------------------------------------------------------------------------
__device__ __forceinline__ void grid_barrier(unsigned* bar, unsigned gen)
{
    __syncthreads();
    if (threadIdx.x == 0) {
        unsigned prev = __hip_atomic_fetch_add(&bar[0], 1u, __ATOMIC_RELAXED,
                                               __HIP_MEMORY_SCOPE_AGENT);
        if (prev == gen * 256u - 1u) {
            __hip_atomic_store(&bar[1], gen, __ATOMIC_RELAXED,
                               __HIP_MEMORY_SCOPE_AGENT);
        } else {
            while (__hip_atomic_load(&bar[1], __ATOMIC_RELAXED,
                                     __HIP_MEMORY_SCOPE_AGENT) < gen) {
                __builtin_amdgcn_s_sleep(2);
            }
        }
    }
    __syncthreads();
    asm volatile("" ::: "memory");
}

// ---------------------------------------------------------------------------
// Persistent LSTM layer, split-bf16 MFMA recurrent matmul.
// Grid = 256 WGs x 256 thr, 1 WG/CU. WG (bt,j0): batches [bt*32,+32) x
// hidden units [j0,+8) x 4 gates (32 gate-rows x 32 batches, K=512).
// W_hh fragments (hi+lo bf16) preloaded to registers ONCE (128 VGPRs/lane).
// Per step: stage h as bf16 hi/lo in LDS, 16 chunks x (2 ds_read_b128 +
// 3 MFMA 16x16x32), exchange preacts via LDS, fp32 elementwise, barrier.
// ---------------------------------------------------------------------------
__global__ __launch_bounds__(256, 1) void lstm_persistent(
    const float* __restrict__ xg,    // [T][B][4H] (biases already added)
    const float* __restrict__ w_hh,  // [4H][H] fp32
    float* __restrict__ hseq,        // [T+1][B][H], block 0 zeroed
    unsigned* __restrict__ bar)
{
    __shared__ short Hs_hi[32][HP2];
    __shared__ short Hs_lo[32][HP2];
    __shared__ float Gs[32][33];

    const int tid  = threadIdx.x;
    const int lane = tid & 63;
    const int wv   = tid >> 6;              // wave 0..3
    const int bt   = blockIdx.x & 3;
    const int j0   = (blockIdx.x >> 2) * 8;

    const int m0   = (wv & 1) * 16;         // gate-row half of 32x32 tile
    const int n0   = (wv >> 1) * 16;        // batch half
    const int l15  = lane & 15;
    const int quad = lane >> 4;

    // ---- preload W_hh fragments (split hi/lo bf16), A-operand layout:
    //      A[m=lane&15][k=quad*8+j], chunk kc covers k=kc*32..+31 ----
    bf16x8 w_hi[16], w_lo[16];
    {
        const int m  = m0 + l15;            // local gate row 0..31
        const int g  = m >> 3, jj = m & 7;  // gate, hidden-unit offset
        const float* wrow = w_hh + (size_t)(g * HH + j0 + jj) * HH + quad * 8;
        #pragma unroll
        for (int kc = 0; kc < 16; ++kc) {
            float f[8];
            *(float4*)&f[0] = *(const float4*)&wrow[kc * 32];
            *(float4*)&f[4] = *(const float4*)&wrow[kc * 32 + 4];
            bf16x8 vh, vl;
            #pragma unroll
            for (int j = 0; j < 8; ++j) {
                unsigned short hb = f2bf(f[j]);
                vh[j] = (short)hb;
                vl[j] = (short)f2bf(f[j] - bf2f(hb));
            }
            w_hi[kc] = vh; w_lo[kc] = vl;
        }
    }

    // update-phase roles: one (b_u, j_u) cell per thread
    const int b_u = tid & 31;
    const int j_u = tid >> 5;

    float c_reg = 0.f;

    for (int t = 0; t < TT; ++t) {
        const float* hsrc = hseq + (size_t)t * (BB * HH) + (size_t)bt * 32 * HH;

        // xg prefetch (independent of h; hides L2 latency under staging)
        const float* xt = xg + (size_t)t * (BB * GG)
                        + (size_t)(bt * 32 + b_u) * GG + j0 + j_u;
        const float xgi = xt[0];
        const float xgf = xt[HH];
        const float xgg = xt[2 * HH];
        const float xgo = xt[3 * HH];

        // ---- stage h (coherent 8B atomic loads -> split bf16 -> LDS) ----
        #pragma unroll 4
        for (int p = 0; p < 16; ++p) {
            const int idx = p * 1024 + tid * 4;     // flat over [32][512]
            const int bb = idx >> 9, kk = idx & 511;
            unsigned long long r0 = __hip_atomic_load(
                (const unsigned long long*)&hsrc[idx],
                __ATOMIC_RELAXED, __HIP_MEMORY_SCOPE_AGENT);
            unsigned long long r1 = __hip_atomic_load(
                (const unsigned long long*)&hsrc[idx + 2],
                __ATOMIC_RELAXED, __HIP_MEMORY_SCOPE_AGENT);
            float2 f01 = __builtin_bit_cast(float2, r0);
            float2 f23 = __builtin_bit_cast(float2, r1);
            unsigned short h0 = f2bf(f01.x), h1 = f2bf(f01.y);
            unsigned short h2 = f2bf(f23.x), h3 = f2bf(f23.y);
            unsigned short e0 = f2bf(f01.x - bf2f(h0)), e1 = f2bf(f01.y - bf2f(h1));
            unsigned short e2 = f2bf(f23.x - bf2f(h2)), e3 = f2bf(f23.y - bf2f(h3));
            unsigned long long hw = (unsigned long long)h0 | ((unsigned long long)h1 << 16)
                                  | ((unsigned long long)h2 << 32) | ((unsigned long long)h3 << 48);
            unsigned long long lw = (unsigned long long)e0 | ((unsigned long long)e1 << 16)
                                  | ((unsigned long long)e2 << 32) | ((unsigned long long)e3 << 48);
            *(unsigned long long*)&Hs_hi[bb][kk] = hw;
            *(unsigned long long*)&Hs_lo[bb][kk] = lw;
        }
        __syncthreads();

        // ---- MFMA mainloop: D[32 gates][32 batches] += Whh . h^T ----
        floatx4 acc0 = {0.f, 0.f, 0.f, 0.f};
        floatx4 acc1 = {0.f, 0.f, 0.f, 0.f};
        const int brow  = n0 + l15;          // B-operand n = batch
        const int kbase = quad * 8;
        #pragma unroll
        for (int kc = 0; kc < 16; kc += 2) {
            bf16x8 bh0 = *(const bf16x8*)&Hs_hi[brow][kc * 32 + kbase];
            bf16x8 bl0 = *(const bf16x8*)&Hs_lo[brow][kc * 32 + kbase];
            bf16x8 bh1 = *(const bf16x8*)&Hs_hi[brow][(kc + 1) * 32 + kbase];
            bf16x8 bl1 = *(const bf16x8*)&Hs_lo[brow][(kc + 1) * 32 + kbase];
            acc0 = __builtin_amdgcn_mfma_f32_16x16x32_bf16(w_hi[kc],     bh0, acc0, 0, 0, 0);
            acc1 = __builtin_amdgcn_mfma_f32_16x16x32_bf16(w_hi[kc + 1], bh1, acc1, 0, 0, 0);
            acc0 = __builtin_amdgcn_mfma_f32_16x16x32_bf16(w_hi[kc],     bl0, acc0, 0, 0, 0);
            acc1 = __builtin_amdgcn_mfma_f32_16x16x32_bf16(w_hi[kc + 1], bl1, acc1, 0, 0, 0);
            acc0 = __builtin_amdgcn_mfma_f32_16x16x32_bf16(w_lo[kc],     bh0, acc0, 0, 0, 0);
            acc1 = __builtin_amdgcn_mfma_f32_16x16x32_bf16(w_lo[kc + 1], bh1, acc1, 0, 0, 0);
        }

        // ---- exchange gate preacts: C/D layout col=lane&15(batch),
        //      row=quad*4+reg(gate-row) ----
        #pragma unroll
        for (int r = 0; r < 4; ++r)
            Gs[m0 + quad * 4 + r][n0 + l15] = acc0[r] + acc1[r];
        __syncthreads();

        // ---- fp32 elementwise update; h out via coherent atomic store ----
        {
            const float gi = Gs[j_u][b_u]      + xgi;   // gate i: row j_u
            const float gf = Gs[8 + j_u][b_u]  + xgf;   // gate f: row 8+j_u
            const float gg = Gs[16 + j_u][b_u] + xgg;   // gate g
            const float go = Gs[24 + j_u][b_u] + xgo;   // gate o
            const float si = 1.f / (1.f + __expf(-gi));
            const float sf = 1.f / (1.f + __expf(-gf));
            const float tg = 2.f / (1.f + __expf(-2.f * gg)) - 1.f;
            const float so = 1.f / (1.f + __expf(-go));
            c_reg = sf * c_reg + si * tg;
            const float th = 2.f / (1.f + __expf(-2.f * c_reg)) - 1.f;
            __hip_atomic_store(
                &hseq[(size_t)(t + 1) * (BB * HH) + (size_t)(bt * 32 + b_u) * HH + j0 + j_u],
                so * th, __ATOMIC_RELAXED, __HIP_MEMORY_SCOPE_AGENT);
        }

        if (t != TT - 1) grid_barrier(bar, (unsigned)(t + 1));
    }
}

// ---------------------------------------------------------------------------
// Classifier split-K partial GEMM (unchanged)
// ---------------------------------------------------------------------------
__global__ __launch_bounds__(256) void cls_partial_kernel(
    const float* __restrict__ A, const float* __restrict__ W,
    float* __restrict__ part)
{
    const int n0 = blockIdx.x * 64;
    const int s  = blockIdx.y;
    const int kbase = s * 2048;
    const int tid = threadIdx.x;
    __shared__ float As[32][68];
    __shared__ float Bs[32][68];
    const int tm = tid >> 4, tn = tid & 15;
    float acc[4][4] = {};

    for (int kt = 0; kt < 2048; kt += 32) {
        #pragma unroll
        for (int q = tid; q < 512; q += 256) {
            const int mm = q >> 3;
            const int kq = q & 7;
            float4 v = *(const float4*)&A[(size_t)mm * KFLAT + kbase + kt + kq * 4];
            As[kq*4+0][mm] = v.x; As[kq*4+1][mm] = v.y;
            As[kq*4+2][mm] = v.z; As[kq*4+3][mm] = v.w;
            float4 w = *(const float4*)&W[(size_t)(n0 + mm) * KFLAT + kbase + kt + kq * 4];
            Bs[kq*4+0][mm] = w.x; Bs[kq*4+1][mm] = w.y;
            Bs[kq*4+2][mm] = w.z; Bs[kq*4+3][mm] = w.w;
        }
        __syncthreads();
        #pragma unroll
        for (int k = 0; k < 32; ++k) {
            float4 a = *(const float4*)&As[k][tm * 4];
            float4 b = *(const float4*)&Bs[k][tn * 4];
            acc[0][0] += a.x*b.x; acc[0][1] += a.x*b.y; acc[0][2] += a.x*b.z; acc[0][3] += a.x*b.w;
            acc[1][0] += a.y*b.x; acc[1][1] += a.y*b.y; acc[1][2] += a.y*b.z; acc[1][3] += a.y*b.w;
            acc[2][0] += a.z*b.x; acc[2][1] += a.z*b.y; acc[2][2] += a.z*b.z; acc[2][3] += a.z*b.w;
            acc[3][0] += a.w*b.x; acc[3][1] += a.w*b.y; acc[3][2] += a.w*b.z; acc[3][3] += a.w*b.w;
        }
        __syncthreads();
    }
    #pragma unroll
    for (int i = 0; i < 4; ++i) {
        const int m = tm * 4 + i;
        #pragma unroll
        for (int j = 0; j < 4; ++j) {
            part[((size_t)s * 64 + m) * 512 + n0 + tn * 4 + j] = acc[i][j];
        }
    }
}

// ---------------------------------------------------------------------------
// Classifier finish (unchanged)
// ---------------------------------------------------------------------------
__global__ __launch_bounds__(256) void cls_final_kernel(
    const float* __restrict__ part, const float* __restrict__ b1,
    const float* __restrict__ w2, const float* __restrict__ b2,
    float* __restrict__ out)
{
    const int t = blockIdx.x;
    __shared__ float hm[512];
    for (int n = threadIdx.x; n < 512; n += 256) {
        float sacc = b1[n];
        for (int sl = 0; sl < 32; ++sl)
            sacc += part[((size_t)sl * 64 + t) * 512 + n];
        hm[n] = fmaxf(sacc, 0.f);
    }
    __syncthreads();
    if (threadIdx.x < NCC) {
        float sacc = b2[threadIdx.x];
        const float* wr = w2 + (size_t)threadIdx.x * 512;
        for (int n = 0; n < 512; ++n) sacc += hm[n] * wr[n];
        out[t * NCC + threadIdx.x] = sacc;
    }
}

// ---------------------------------------------------------------------------
extern "C" void kernel_launch(void* const* d_in, const int* in_sizes, int n_in,
                              void* d_out, int out_size, void* d_ws, size_t ws_size,
                              hipStream_t stream)
{
    const float* x     = (const float*)d_in[0];
    const float* w_ih0 = (const float*)d_in[1];
    const float* w_hh0 = (const float*)d_in[2];
    const float* b_ih0 = (const float*)d_in[3];
    const float* b_hh0 = (const float*)d_in[4];
    const float* w_ih1 = (const float*)d_in[5];
    const float* w_hh1 = (const float*)d_in[6];
    const float* b_ih1 = (const float*)d_in[7];
    const float* b_hh1 = (const float*)d_in[8];
    const float* w1    = (const float*)d_in[9];
    const float* b1    = (const float*)d_in[10];
    const float* w2    = (const float*)d_in[11];
    const float* b2    = (const float*)d_in[12];
    float* out = (float*)d_out;

    // Workspace layout (floats)
    float* ws    = (float*)d_ws;
    float* xg    = ws;                            // [8192,2048]   = 16,777,216
    float* hseq0 = xg + (size_t)8192 * 2048;      // [65][128][512]=  4,259,840
    float* hseq1 = hseq0 + (size_t)65 * BB * HH;  // [65][128][512]=  4,259,840
    float* part  = hseq1 + (size_t)65 * BB * HH;  // [32][64][512] =  1,048,576
    unsigned* bar = (unsigned*)(part + (size_t)32 * 64 * 512);  // 2 uints

    hipMemsetAsync(hseq0, 0, (size_t)BB * HH * sizeof(float), stream);
    hipMemsetAsync(hseq1, 0, (size_t)BB * HH * sizeof(float), stream);
    hipMemsetAsync(bar, 0, 2 * sizeof(unsigned), stream);

    // ---- layer 0 ----
    gemm_bias_kernel<<<dim3(8192 / 64, GG / 64), 256, 0, stream>>>(
        x, w_ih0, b_ih0, b_hh0, xg, IND, GG);
    lstm_persistent<<<256, 256, 0, stream>>>(xg, w_hh0, hseq0, bar);

    // ---- layer 1 ----
    gemm_bias_kernel<<<dim3(8192 / 64, GG / 64), 256, 0, stream>>>(
        hseq0 + (size_t)BB * HH, w_ih1, b_ih1, b_hh1, xg, HH, GG);
    hipMemsetAsync(bar, 0, 2 * sizeof(unsigned), stream);
    lstm_persistent<<<256, 256, 0, stream>>>(xg, w_hh1, hseq1, bar);

    // ---- classifier ----
    cls_partial_kernel<<<dim3(512 / 64, 32), 256, 0, stream>>>(
        hseq1 + (size_t)BB * HH, w1, part);
    cls_final_kernel<<<64, 256, 0, stream>>>(part, b1, w2, b2, out);
}

// Round 5
// 1549.093 us; speedup vs baseline: 5.7049x; 1.3677x over previous
//
#include <hip/hip_runtime.h>

// Problem constants (reference: T=64 time steps, B=SEQ=128 batch, IN=256, H=512)
#define TT 64
#define BB 128
#define IND 256
#define HH 512
#define GG 2048      // 4*H
#define NCC 10
#define KFLAT 65536  // SEQ*H
#define HP2 520      // bf16 LDS row stride (512 + 8)

typedef __attribute__((ext_vector_type(8))) short bf16x8;   // 8 bf16 in 4 VGPRs
typedef __attribute__((ext_vector_type(4))) float floatx4;  // MFMA accumulator

__device__ __forceinline__ unsigned short f2bf(float x) {   // RNE round to bf16
    unsigned u = __builtin_bit_cast(unsigned, x);
    u += 0x7fffu + ((u >> 16) & 1u);
    return (unsigned short)(u >> 16);
}
__device__ __forceinline__ float bf2f(unsigned short h) {
    unsigned u = ((unsigned)h) << 16;
    return __builtin_bit_cast(float, u);
}
// packed u32 (hi<<16 | lo) -> fp32 (hi + lo)
__device__ __forceinline__ float pk2f(unsigned u) {
    float hi = __builtin_bit_cast(float, u & 0xffff0000u);
    float lo = __builtin_bit_cast(float, u << 16);
    return hi + lo;
}

// ---------------------------------------------------------------------------
// GEMM: C[m,n] = sum_k A[m,k]*W[n,k] + b0[n] + b1[n]   (unchanged; R6 target)
// ---------------------------------------------------------------------------
__global__ __launch_bounds__(256) void gemm_bias_kernel(
    const float* __restrict__ A, const float* __restrict__ W,
    const float* __restrict__ b0, const float* __restrict__ b1,
    float* __restrict__ C, int K, int N)
{
    const int m0 = blockIdx.x * 64;
    const int n0 = blockIdx.y * 64;
    const int tid = threadIdx.x;
    __shared__ float As[32][68];
    __shared__ float Bs[32][68];
    const int tm = tid >> 4;
    const int tn = tid & 15;
    float acc[4][4] = {};

    for (int kt = 0; kt < K; kt += 32) {
        #pragma unroll
        for (int q = tid; q < 512; q += 256) {
            const int mm = q >> 3;
            const int kq = q & 7;
            float4 v = *(const float4*)&A[(size_t)(m0 + mm) * K + kt + kq * 4];
            As[kq*4+0][mm] = v.x; As[kq*4+1][mm] = v.y;
            As[kq*4+2][mm] = v.z; As[kq*4+3][mm] = v.w;
            float4 w = *(const float4*)&W[(size_t)(n0 + mm) * K + kt + kq * 4];
            Bs[kq*4+0][mm] = w.x; Bs[kq*4+1][mm] = w.y;
            Bs[kq*4+2][mm] = w.z; Bs[kq*4+3][mm] = w.w;
        }
        __syncthreads();
        #pragma unroll
        for (int k = 0; k < 32; ++k) {
            float4 a = *(const float4*)&As[k][tm * 4];
            float4 b = *(const float4*)&Bs[k][tn * 4];
            acc[0][0] += a.x*b.x; acc[0][1] += a.x*b.y; acc[0][2] += a.x*b.z; acc[0][3] += a.x*b.w;
            acc[1][0] += a.y*b.x; acc[1][1] += a.y*b.y; acc[1][2] += a.y*b.z; acc[1][3] += a.y*b.w;
            acc[2][0] += a.z*b.x; acc[2][1] += a.z*b.y; acc[2][2] += a.z*b.z; acc[2][3] += a.z*b.w;
            acc[3][0] += a.w*b.x; acc[3][1] += a.w*b.y; acc[3][2] += a.w*b.z; acc[3][3] += a.w*b.w;
        }
        __syncthreads();
    }
    #pragma unroll
    for (int i = 0; i < 4; ++i) {
        const int m = m0 + tm * 4 + i;
        #pragma unroll
        for (int j = 0; j < 4; ++j) {
            const int n = n0 + tn * 4 + j;
            C[(size_t)m * N + n] = acc[i][j] + b0[n] + b1[n];
        }
    }
}

// ---------------------------------------------------------------------------
// Contention-free grid barrier. slots[i*4] = WG i's arrival gen (monotone,
// 16B apart); slots[1024] = published gen flag. Arrivals are parallel plain
// atomic stores (no RMW serialization). WG0 sweeps all 256 slots with 256
// threads + __syncthreads_and, then publishes. All relaxed agent scope (IF$
// point, no L2 invalidates). 256 WGs x 71KB LDS -> exactly 1 WG/CU, fully
// co-resident (proven R2-R4).
// ---------------------------------------------------------------------------
__device__ __forceinline__ void grid_barrier(unsigned* slots, unsigned gen)
{
    __syncthreads();   // all lanes done; h stores drained (vmcnt0 before s_barrier)
    if (blockIdx.x == 0) {
        if (threadIdx.x == 0)
            __hip_atomic_store(&slots[0], gen, __ATOMIC_RELAXED,
                               __HIP_MEMORY_SCOPE_AGENT);
        const unsigned* my = &slots[threadIdx.x * 4];
        int ok;
        do {
            unsigned v = __hip_atomic_load(my, __ATOMIC_RELAXED,
                                           __HIP_MEMORY_SCOPE_AGENT);
            ok = __syncthreads_and((int)(v >= gen));
        } while (!ok);
        if (threadIdx.x == 0)
            __hip_atomic_store(&slots[1024], gen, __ATOMIC_RELAXED,
                               __HIP_MEMORY_SCOPE_AGENT);
    } else {
        if (threadIdx.x == 0) {
            __hip_atomic_store(&slots[blockIdx.x * 4], gen, __ATOMIC_RELAXED,
                               __HIP_MEMORY_SCOPE_AGENT);
            while (__hip_atomic_load(&slots[1024], __ATOMIC_RELAXED,
                                     __HIP_MEMORY_SCOPE_AGENT) < gen) {
                __builtin_amdgcn_s_sleep(1);
            }
        }
        __syncthreads();
    }
    asm volatile("" ::: "memory");
}

// ---------------------------------------------------------------------------
// Persistent LSTM layer, split-bf16 MFMA. W_hh frags in registers across all
// 64 steps. h exchanged as PACKED u32 (bf16 hi<<16 | lo) via IF$ atomics --
// producer packs once, consumers unpack with shifts (no float math).
// fp32 h additionally written with plain cached stores for the next-layer
// GEMM (cross-kernel visibility via launch-boundary flush).
// ---------------------------------------------------------------------------
__global__ __launch_bounds__(256, 1) void lstm_persistent(
    const float* __restrict__ xg,     // [T][B][4H] (biases already added)
    const float* __restrict__ w_hh,   // [4H][H] fp32
    float* __restrict__ hseq,         // [T+1][B][H] fp32 out (plain stores)
    unsigned* __restrict__ hpack,     // [T+1][B][H] packed, block 0 zeroed
    unsigned* __restrict__ slots,     // barrier slots/flag
    int gen_base)
{
    __shared__ short Hs_hi[32][HP2];
    __shared__ short Hs_lo[32][HP2];
    __shared__ float Gs[32][33];

    const int tid  = threadIdx.x;
    const int lane = tid & 63;
    const int wv   = tid >> 6;              // wave 0..3
    const int bt   = blockIdx.x & 3;
    const int j0   = (blockIdx.x >> 2) * 8;

    const int m0   = (wv & 1) * 16;         // gate-row half of 32x32 tile
    const int n0   = (wv >> 1) * 16;        // batch half
    const int l15  = lane & 15;
    const int quad = lane >> 4;

    // ---- preload W_hh fragments (split hi/lo bf16), A-operand layout ----
    bf16x8 w_hi[16], w_lo[16];
    {
        const int m  = m0 + l15;
        const int g  = m >> 3, jj = m & 7;
        const float* wrow = w_hh + (size_t)(g * HH + j0 + jj) * HH + quad * 8;
        #pragma unroll
        for (int kc = 0; kc < 16; ++kc) {
            float f[8];
            *(float4*)&f[0] = *(const float4*)&wrow[kc * 32];
            *(float4*)&f[4] = *(const float4*)&wrow[kc * 32 + 4];
            bf16x8 vh, vl;
            #pragma unroll
            for (int j = 0; j < 8; ++j) {
                unsigned short hb = f2bf(f[j]);
                vh[j] = (short)hb;
                vl[j] = (short)f2bf(f[j] - bf2f(hb));
            }
            w_hi[kc] = vh; w_lo[kc] = vl;
        }
    }

    // update-phase roles: one (b_u, j_u) cell per thread
    const int b_u = tid & 31;
    const int j_u = tid >> 5;

    float c_reg = 0.f;

    for (int t = 0; t < TT; ++t) {
        const unsigned* hsrc = hpack + (size_t)t * (BB * HH) + (size_t)bt * 32 * HH;

        // xg prefetch (independent of h; overlaps staging latency)
        const float* xt = xg + (size_t)t * (BB * GG)
                        + (size_t)(bt * 32 + b_u) * GG + j0 + j_u;
        const float xgi = xt[0];
        const float xgf = xt[HH];
        const float xgg = xt[2 * HH];
        const float xgo = xt[3 * HH];

        // ---- stage h: coherent 8B loads of packed u32s -> shift-unpack ----
        #pragma unroll
        for (int p = 0; p < 8; ++p) {
            const int idx = p * 2048 + tid * 8;     // cell index over [32][512]
            const int bb = idx >> 9, kk = idx & 511;
            const unsigned long long* src = (const unsigned long long*)&hsrc[idx];
            unsigned long long q0 = __hip_atomic_load(src + 0, __ATOMIC_RELAXED, __HIP_MEMORY_SCOPE_AGENT);
            unsigned long long q1 = __hip_atomic_load(src + 1, __ATOMIC_RELAXED, __HIP_MEMORY_SCOPE_AGENT);
            unsigned long long q2 = __hip_atomic_load(src + 2, __ATOMIC_RELAXED, __HIP_MEMORY_SCOPE_AGENT);
            unsigned long long q3 = __hip_atomic_load(src + 3, __ATOMIC_RELAXED, __HIP_MEMORY_SCOPE_AGENT);
            unsigned c0 = (unsigned)q0, c1 = (unsigned)(q0 >> 32);
            unsigned c2 = (unsigned)q1, c3 = (unsigned)(q1 >> 32);
            unsigned c4 = (unsigned)q2, c5 = (unsigned)(q2 >> 32);
            unsigned c6 = (unsigned)q3, c7 = (unsigned)(q3 >> 32);
            uint4 hiv, lov;
            hiv.x = (c0 >> 16) | (c1 & 0xffff0000u);
            hiv.y = (c2 >> 16) | (c3 & 0xffff0000u);
            hiv.z = (c4 >> 16) | (c5 & 0xffff0000u);
            hiv.w = (c6 >> 16) | (c7 & 0xffff0000u);
            lov.x = (c0 & 0xffffu) | (c1 << 16);
            lov.y = (c2 & 0xffffu) | (c3 << 16);
            lov.z = (c4 & 0xffffu) | (c5 << 16);
            lov.w = (c6 & 0xffffu) | (c7 << 16);
            *(uint4*)&Hs_hi[bb][kk] = hiv;
            *(uint4*)&Hs_lo[bb][kk] = lov;
        }
        __syncthreads();

        // ---- MFMA mainloop: D[32 gates][32 batches] += Whh . h^T ----
        floatx4 acc0 = {0.f, 0.f, 0.f, 0.f};
        floatx4 acc1 = {0.f, 0.f, 0.f, 0.f};
        const int brow  = n0 + l15;
        const int kbase = quad * 8;
        #pragma unroll
        for (int kc = 0; kc < 16; kc += 2) {
            bf16x8 bh0 = *(const bf16x8*)&Hs_hi[brow][kc * 32 + kbase];
            bf16x8 bl0 = *(const bf16x8*)&Hs_lo[brow][kc * 32 + kbase];
            bf16x8 bh1 = *(const bf16x8*)&Hs_hi[brow][(kc + 1) * 32 + kbase];
            bf16x8 bl1 = *(const bf16x8*)&Hs_lo[brow][(kc + 1) * 32 + kbase];
            acc0 = __builtin_amdgcn_mfma_f32_16x16x32_bf16(w_hi[kc],     bh0, acc0, 0, 0, 0);
            acc1 = __builtin_amdgcn_mfma_f32_16x16x32_bf16(w_hi[kc + 1], bh1, acc1, 0, 0, 0);
            acc0 = __builtin_amdgcn_mfma_f32_16x16x32_bf16(w_hi[kc],     bl0, acc0, 0, 0, 0);
            acc1 = __builtin_amdgcn_mfma_f32_16x16x32_bf16(w_hi[kc + 1], bl1, acc1, 0, 0, 0);
            acc0 = __builtin_amdgcn_mfma_f32_16x16x32_bf16(w_lo[kc],     bh0, acc0, 0, 0, 0);
            acc1 = __builtin_amdgcn_mfma_f32_16x16x32_bf16(w_lo[kc + 1], bh1, acc1, 0, 0, 0);
        }

        // ---- exchange gate preacts (C/D: col=lane&15 batch, row=quad*4+r) ----
        #pragma unroll
        for (int r = 0; r < 4; ++r)
            Gs[m0 + quad * 4 + r][n0 + l15] = acc0[r] + acc1[r];
        __syncthreads();

        // ---- fp32 elementwise update; pack + store ----
        {
            const float gi = Gs[j_u][b_u]      + xgi;
            const float gf = Gs[8 + j_u][b_u]  + xgf;
            const float gg = Gs[16 + j_u][b_u] + xgg;
            const float go = Gs[24 + j_u][b_u] + xgo;
            const float si = 1.f / (1.f + __expf(-gi));
            const float sf = 1.f / (1.f + __expf(-gf));
            const float tg = 2.f / (1.f + __expf(-2.f * gg)) - 1.f;
            const float so = 1.f / (1.f + __expf(-go));
            c_reg = sf * c_reg + si * tg;
            const float th = 2.f / (1.f + __expf(-2.f * c_reg)) - 1.f;
            const float hval = so * th;
            const size_t row = (size_t)(bt * 32 + b_u) * HH + j0 + j_u;
            hseq[(size_t)(t + 1) * (BB * HH) + row] = hval;   // plain fp32 (next-layer GEMM)
            const unsigned short hb = f2bf(hval);
            const unsigned short lb = f2bf(hval - bf2f(hb));
            const unsigned pk = ((unsigned)hb << 16) | (unsigned)lb;
            __hip_atomic_store(&hpack[(size_t)(t + 1) * (BB * HH) + row], pk,
                               __ATOMIC_RELAXED, __HIP_MEMORY_SCOPE_AGENT);
        }

        if (t != TT - 1) grid_barrier(slots, (unsigned)(gen_base + t + 1));
    }
}

// ---------------------------------------------------------------------------
// Classifier split-K partial GEMM. A is now the PACKED h buffer (blocks
// 1..64): reconstruct fp32 = hi + lo during staging.
// ---------------------------------------------------------------------------
__global__ __launch_bounds__(256) void cls_partial_kernel(
    const unsigned* __restrict__ A, const float* __restrict__ W,
    float* __restrict__ part)
{
    const int n0 = blockIdx.x * 64;
    const int s  = blockIdx.y;
    const int kbase = s * 2048;
    const int tid = threadIdx.x;
    __shared__ float As[32][68];
    __shared__ float Bs[32][68];
    const int tm = tid >> 4, tn = tid & 15;
    float acc[4][4] = {};

    for (int kt = 0; kt < 2048; kt += 32) {
        #pragma unroll
        for (int q = tid; q < 512; q += 256) {
            const int mm = q >> 3;
            const int kq = q & 7;
            uint4 v = *(const uint4*)&A[(size_t)mm * KFLAT + kbase + kt + kq * 4];
            As[kq*4+0][mm] = pk2f(v.x); As[kq*4+1][mm] = pk2f(v.y);
            As[kq*4+2][mm] = pk2f(v.z); As[kq*4+3][mm] = pk2f(v.w);
            float4 w = *(const float4*)&W[(size_t)(n0 + mm) * KFLAT + kbase + kt + kq * 4];
            Bs[kq*4+0][mm] = w.x; Bs[kq*4+1][mm] = w.y;
            Bs[kq*4+2][mm] = w.z; Bs[kq*4+3][mm] = w.w;
        }
        __syncthreads();
        #pragma unroll
        for (int k = 0; k < 32; ++k) {
            float4 a = *(const float4*)&As[k][tm * 4];
            float4 b = *(const float4*)&Bs[k][tn * 4];
            acc[0][0] += a.x*b.x; acc[0][1] += a.x*b.y; acc[0][2] += a.x*b.z; acc[0][3] += a.x*b.w;
            acc[1][0] += a.y*b.x; acc[1][1] += a.y*b.y; acc[1][2] += a.y*b.z; acc[1][3] += a.y*b.w;
            acc[2][0] += a.z*b.x; acc[2][1] += a.z*b.y; acc[2][2] += a.z*b.z; acc[2][3] += a.z*b.w;
            acc[3][0] += a.w*b.x; acc[3][1] += a.w*b.y; acc[3][2] += a.w*b.z; acc[3][3] += a.w*b.w;
        }
        __syncthreads();
    }
    #pragma unroll
    for (int i = 0; i < 4; ++i) {
        const int m = tm * 4 + i;
        #pragma unroll
        for (int j = 0; j < 4; ++j) {
            part[((size_t)s * 64 + m) * 512 + n0 + tn * 4 + j] = acc[i][j];
        }
    }
}

// ---------------------------------------------------------------------------
// Classifier finish (unchanged)
// ---------------------------------------------------------------------------
__global__ __launch_bounds__(256) void cls_final_kernel(
    const float* __restrict__ part, const float* __restrict__ b1,
    const float* __restrict__ w2, const float* __restrict__ b2,
    float* __restrict__ out)
{
    const int t = blockIdx.x;
    __shared__ float hm[512];
    for (int n = threadIdx.x; n < 512; n += 256) {
        float sacc = b1[n];
        for (int sl = 0; sl < 32; ++sl)
            sacc += part[((size_t)sl * 64 + t) * 512 + n];
        hm[n] = fmaxf(sacc, 0.f);
    }
    __syncthreads();
    if (threadIdx.x < NCC) {
        float sacc = b2[threadIdx.x];
        const float* wr = w2 + (size_t)threadIdx.x * 512;
        for (int n = 0; n < 512; ++n) sacc += hm[n] * wr[n];
        out[t * NCC + threadIdx.x] = sacc;
    }
}

// ---------------------------------------------------------------------------
extern "C" void kernel_launch(void* const* d_in, const int* in_sizes, int n_in,
                              void* d_out, int out_size, void* d_ws, size_t ws_size,
                              hipStream_t stream)
{
    const float* x     = (const float*)d_in[0];
    const float* w_ih0 = (const float*)d_in[1];
    const float* w_hh0 = (const float*)d_in[2];
    const float* b_ih0 = (const float*)d_in[3];
    const float* b_hh0 = (const float*)d_in[4];
    const float* w_ih1 = (const float*)d_in[5];
    const float* w_hh1 = (const float*)d_in[6];
    const float* b_ih1 = (const float*)d_in[7];
    const float* b_hh1 = (const float*)d_in[8];
    const float* w1    = (const float*)d_in[9];
    const float* b1    = (const float*)d_in[10];
    const float* w2    = (const float*)d_in[11];
    const float* b2    = (const float*)d_in[12];
    float* out = (float*)d_out;

    // Workspace layout (ws_size budget ~100.5 MB, within R0 footprint)
    float* ws      = (float*)d_ws;
    float* xg      = ws;                              // [8192,2048]    64 MB
    float* hseq    = xg + (size_t)8192 * 2048;        // [65][128][512] 16.25 MB fp32
    unsigned* hpack = (unsigned*)(hseq + (size_t)65 * BB * HH);  // 16.25 MB packed
    float* part    = (float*)(hpack + (size_t)65 * BB * HH);     // [32][64][512] 4 MB
    unsigned* slots = (unsigned*)(part + (size_t)32 * 64 * 512); // 256 slots + flag

    // re-init per call (ws re-poisoned to 0xAA before every timed launch)
    hipMemsetAsync(hpack, 0, (size_t)BB * HH * sizeof(unsigned), stream);  // t=0 block
    hipMemsetAsync(slots, 0, 1028 * sizeof(unsigned), stream);

    // ---- layer 0 ----
    gemm_bias_kernel<<<dim3(8192 / 64, GG / 64), 256, 0, stream>>>(
        x, w_ih0, b_ih0, b_hh0, xg, IND, GG);
    lstm_persistent<<<256, 256, 0, stream>>>(xg, w_hh0, hseq, hpack, slots, 0);

    // ---- layer 1 (reads fp32 hseq blocks 1..64; lstm1 re-dumps into hseq) ----
    gemm_bias_kernel<<<dim3(8192 / 64, GG / 64), 256, 0, stream>>>(
        hseq + (size_t)BB * HH, w_ih1, b_ih1, b_hh1, xg, HH, GG);
    lstm_persistent<<<256, 256, 0, stream>>>(xg, w_hh1, hseq, hpack, slots, 64);

    // ---- classifier (reads packed h of layer 1, blocks 1..64) ----
    cls_partial_kernel<<<dim3(512 / 64, 32), 256, 0, stream>>>(
        hpack + (size_t)BB * HH, w1, part);
    cls_final_kernel<<<64, 256, 0, stream>>>(part, b1, w2, b2, out);
}

// Round 6
// 1280.759 us; speedup vs baseline: 6.9001x; 1.2095x over previous
//
#include <hip/hip_runtime.h>

// Problem constants (reference: T=64 time steps, B=SEQ=128 batch, IN=256, H=512)
#define TT 64
#define BB 128
#define IND 256
#define HH 512
#define GG 2048      // 4*H
#define NCC 10
#define KFLAT 65536  // SEQ*H
#define HP2 520      // bf16 LDS row stride in lstm kernel (512 + 8)
#define SP 36        // GEMM LDS short stride (32 data + 4 pad -> 18-bank row shift)

typedef __attribute__((ext_vector_type(8))) short bf16x8;   // 8 bf16 in 4 VGPRs
typedef __attribute__((ext_vector_type(4))) float floatx4;  // MFMA accumulator

__device__ __forceinline__ unsigned short f2bf(float x) {   // RNE round to bf16
    unsigned u = __builtin_bit_cast(unsigned, x);
    u += 0x7fffu + ((u >> 16) & 1u);
    return (unsigned short)(u >> 16);
}
__device__ __forceinline__ float bf2f(unsigned short h) {
    unsigned u = ((unsigned)h) << 16;
    return __builtin_bit_cast(float, u);
}
// packed u32 (hi<<16 | lo) -> fp32 (hi + lo)
__device__ __forceinline__ float pk2f(unsigned u) {
    float hi = __builtin_bit_cast(float, u & 0xffff0000u);
    float lo = __builtin_bit_cast(float, u << 16);
    return hi + lo;
}

// ---------------------------------------------------------------------------
// Elementwise: fp32 -> packed split-bf16 (hi<<16 | lo)
// ---------------------------------------------------------------------------
__global__ __launch_bounds__(256) void pack_split_kernel(
    const float* __restrict__ src, unsigned* __restrict__ dst, int n)
{
    for (int i = blockIdx.x * 256 + threadIdx.x; i < n; i += gridDim.x * 256) {
        float f = src[i];
        unsigned short hb = f2bf(f);
        unsigned short lb = f2bf(f - bf2f(hb));
        dst[i] = ((unsigned)hb << 16) | lb;
    }
}

// ---------------------------------------------------------------------------
// MFMA GEMM on packed split-bf16: C[m,n] = sum_k A[m,k]*W[n,k] + b0[n]+b1[n]
// A:[M][K], W:[N][K] packed u32. 128x128 tile, 4 waves (2x2 of 64x64),
// k-chunk 32. 3 MFMA per tile per chunk (hi*hi + hi*lo + lo*hi);
// lo*lo dropped (~2^-32, far below fp32 epsilon of the sum).
// ---------------------------------------------------------------------------
__global__ __launch_bounds__(256) void gemm_pk_mfma(
    const unsigned* __restrict__ A, const unsigned* __restrict__ W,
    const float* __restrict__ b0, const float* __restrict__ b1,
    float* __restrict__ C, int K, int N)
{
    __shared__ short Ahi[128][SP], Alo[128][SP], Whi[128][SP], Wlo[128][SP];

    const int tid  = threadIdx.x;
    const int lane = tid & 63;
    const int wv   = tid >> 6;
    const int wm   = (wv & 1) * 64;
    const int wn   = (wv >> 1) * 64;
    const int l15  = lane & 15;
    const int quad = lane >> 4;
    const int m0   = blockIdx.x * 128;
    const int n0   = blockIdx.y * 128;

    floatx4 acc[4][4];
    #pragma unroll
    for (int i = 0; i < 4; ++i)
        #pragma unroll
        for (int j = 0; j < 4; ++j)
            acc[i][j] = (floatx4){0.f, 0.f, 0.f, 0.f};

    for (int kc = 0; kc < K; kc += 32) {
        // ---- stage A-tile and W-tile: packed u32 -> hi/lo bf16 LDS planes ----
        #pragma unroll
        for (int it = 0; it < 4; ++it) {
            const int lin = it * 256 + tid;          // 0..1023
            const int row = lin >> 3;                // 0..127
            const int c4  = (lin & 7) * 4;           // element col (x4)
            uint4 va = *(const uint4*)&A[(size_t)(m0 + row) * K + kc + c4];
            uint2 ah, al;
            ah.x = (va.x >> 16) | (va.y & 0xffff0000u);
            ah.y = (va.z >> 16) | (va.w & 0xffff0000u);
            al.x = (va.x & 0xffffu) | (va.y << 16);
            al.y = (va.z & 0xffffu) | (va.w << 16);
            *(uint2*)&Ahi[row][c4] = ah;
            *(uint2*)&Alo[row][c4] = al;
            uint4 vw = *(const uint4*)&W[(size_t)(n0 + row) * K + kc + c4];
            uint2 wh, wl;
            wh.x = (vw.x >> 16) | (vw.y & 0xffff0000u);
            wh.y = (vw.z >> 16) | (vw.w & 0xffff0000u);
            wl.x = (vw.x & 0xffffu) | (vw.y << 16);
            wl.y = (vw.z & 0xffffu) | (vw.w << 16);
            *(uint2*)&Whi[row][c4] = wh;
            *(uint2*)&Wlo[row][c4] = wl;
        }
        __syncthreads();

        // ---- fragments + 48 MFMA ----
        bf16x8 afh[4], afl[4], bfh[4], bfl[4];
        #pragma unroll
        for (int i = 0; i < 4; ++i) {
            afh[i] = *(const bf16x8*)&Ahi[wm + i * 16 + l15][quad * 8];
            afl[i] = *(const bf16x8*)&Alo[wm + i * 16 + l15][quad * 8];
            bfh[i] = *(const bf16x8*)&Whi[wn + i * 16 + l15][quad * 8];
            bfl[i] = *(const bf16x8*)&Wlo[wn + i * 16 + l15][quad * 8];
        }
        #pragma unroll
        for (int i = 0; i < 4; ++i)
            #pragma unroll
            for (int j = 0; j < 4; ++j) {
                acc[i][j] = __builtin_amdgcn_mfma_f32_16x16x32_bf16(afh[i], bfh[j], acc[i][j], 0, 0, 0);
                acc[i][j] = __builtin_amdgcn_mfma_f32_16x16x32_bf16(afh[i], bfl[j], acc[i][j], 0, 0, 0);
                acc[i][j] = __builtin_amdgcn_mfma_f32_16x16x32_bf16(afl[i], bfh[j], acc[i][j], 0, 0, 0);
            }
        __syncthreads();
    }

    // ---- epilogue: C/D layout col=lane&15 (n), row=quad*4+r (m) ----
    #pragma unroll
    for (int i = 0; i < 4; ++i) {
        #pragma unroll
        for (int j = 0; j < 4; ++j) {
            const int n = n0 + wn + j * 16 + l15;
            const float bias = b0[n] + b1[n];
            #pragma unroll
            for (int r = 0; r < 4; ++r) {
                const int m = m0 + wm + i * 16 + quad * 4 + r;
                C[(size_t)m * N + n] = acc[i][j][r] + bias;
            }
        }
    }
}

// ---------------------------------------------------------------------------
// Contention-free grid barrier (proven R5). slots[i*4] = WG i arrival gen
// (monotone); slots[1024] = published gen. Relaxed agent atomics only.
// ---------------------------------------------------------------------------
__device__ __forceinline__ void grid_barrier(unsigned* slots, unsigned gen)
{
    __syncthreads();
    if (blockIdx.x == 0) {
        if (threadIdx.x == 0)
            __hip_atomic_store(&slots[0], gen, __ATOMIC_RELAXED,
                               __HIP_MEMORY_SCOPE_AGENT);
        const unsigned* my = &slots[threadIdx.x * 4];
        int ok;
        do {
            unsigned v = __hip_atomic_load(my, __ATOMIC_RELAXED,
                                           __HIP_MEMORY_SCOPE_AGENT);
            ok = __syncthreads_and((int)(v >= gen));
        } while (!ok);
        if (threadIdx.x == 0)
            __hip_atomic_store(&slots[1024], gen, __ATOMIC_RELAXED,
                               __HIP_MEMORY_SCOPE_AGENT);
    } else {
        if (threadIdx.x == 0) {
            __hip_atomic_store(&slots[blockIdx.x * 4], gen, __ATOMIC_RELAXED,
                               __HIP_MEMORY_SCOPE_AGENT);
            while (__hip_atomic_load(&slots[1024], __ATOMIC_RELAXED,
                                     __HIP_MEMORY_SCOPE_AGENT) < gen) {
                __builtin_amdgcn_s_sleep(1);
            }
        }
        __syncthreads();
    }
    asm volatile("" ::: "memory");
}

// ---------------------------------------------------------------------------
// Persistent LSTM layer, split-bf16 MFMA (proven R4/R5). h exchanged ONLY as
// packed u32 now (fp32 hseq deleted -- layer-1 GEMM consumes hpack directly).
// ---------------------------------------------------------------------------
__global__ __launch_bounds__(256, 1) void lstm_persistent(
    const float* __restrict__ xg,     // [T][B][4H] (biases already added)
    const float* __restrict__ w_hh,   // [4H][H] fp32
    unsigned* __restrict__ hpack,     // [T+1][B][H] packed, block 0 zeroed
    unsigned* __restrict__ slots,     // barrier slots/flag
    int gen_base)
{
    __shared__ short Hs_hi[32][HP2];
    __shared__ short Hs_lo[32][HP2];
    __shared__ float Gs[32][33];

    const int tid  = threadIdx.x;
    const int lane = tid & 63;
    const int wv   = tid >> 6;
    const int bt   = blockIdx.x & 3;
    const int j0   = (blockIdx.x >> 2) * 8;

    const int m0   = (wv & 1) * 16;
    const int n0   = (wv >> 1) * 16;
    const int l15  = lane & 15;
    const int quad = lane >> 4;

    // ---- preload W_hh fragments (split hi/lo bf16), A-operand layout ----
    bf16x8 w_hi[16], w_lo[16];
    {
        const int m  = m0 + l15;
        const int g  = m >> 3, jj = m & 7;
        const float* wrow = w_hh + (size_t)(g * HH + j0 + jj) * HH + quad * 8;
        #pragma unroll
        for (int kc = 0; kc < 16; ++kc) {
            float f[8];
            *(float4*)&f[0] = *(const float4*)&wrow[kc * 32];
            *(float4*)&f[4] = *(const float4*)&wrow[kc * 32 + 4];
            bf16x8 vh, vl;
            #pragma unroll
            for (int j = 0; j < 8; ++j) {
                unsigned short hb = f2bf(f[j]);
                vh[j] = (short)hb;
                vl[j] = (short)f2bf(f[j] - bf2f(hb));
            }
            w_hi[kc] = vh; w_lo[kc] = vl;
        }
    }

    const int b_u = tid & 31;
    const int j_u = tid >> 5;

    float c_reg = 0.f;

    for (int t = 0; t < TT; ++t) {
        const unsigned* hsrc = hpack + (size_t)t * (BB * HH) + (size_t)bt * 32 * HH;

        const float* xt = xg + (size_t)t * (BB * GG)
                        + (size_t)(bt * 32 + b_u) * GG + j0 + j_u;
        const float xgi = xt[0];
        const float xgf = xt[HH];
        const float xgg = xt[2 * HH];
        const float xgo = xt[3 * HH];

        // ---- stage h: coherent 8B loads of packed u32s -> shift-unpack ----
        #pragma unroll
        for (int p = 0; p < 8; ++p) {
            const int idx = p * 2048 + tid * 8;
            const int bb = idx >> 9, kk = idx & 511;
            const unsigned long long* src = (const unsigned long long*)&hsrc[idx];
            unsigned long long q0 = __hip_atomic_load(src + 0, __ATOMIC_RELAXED, __HIP_MEMORY_SCOPE_AGENT);
            unsigned long long q1 = __hip_atomic_load(src + 1, __ATOMIC_RELAXED, __HIP_MEMORY_SCOPE_AGENT);
            unsigned long long q2 = __hip_atomic_load(src + 2, __ATOMIC_RELAXED, __HIP_MEMORY_SCOPE_AGENT);
            unsigned long long q3 = __hip_atomic_load(src + 3, __ATOMIC_RELAXED, __HIP_MEMORY_SCOPE_AGENT);
            unsigned c0 = (unsigned)q0, c1 = (unsigned)(q0 >> 32);
            unsigned c2 = (unsigned)q1, c3 = (unsigned)(q1 >> 32);
            unsigned c4 = (unsigned)q2, c5 = (unsigned)(q2 >> 32);
            unsigned c6 = (unsigned)q3, c7 = (unsigned)(q3 >> 32);
            uint4 hiv, lov;
            hiv.x = (c0 >> 16) | (c1 & 0xffff0000u);
            hiv.y = (c2 >> 16) | (c3 & 0xffff0000u);
            hiv.z = (c4 >> 16) | (c5 & 0xffff0000u);
            hiv.w = (c6 >> 16) | (c7 & 0xffff0000u);
            lov.x = (c0 & 0xffffu) | (c1 << 16);
            lov.y = (c2 & 0xffffu) | (c3 << 16);
            lov.z = (c4 & 0xffffu) | (c5 << 16);
            lov.w = (c6 & 0xffffu) | (c7 << 16);
            *(uint4*)&Hs_hi[bb][kk] = hiv;
            *(uint4*)&Hs_lo[bb][kk] = lov;
        }
        __syncthreads();

        // ---- MFMA mainloop ----
        floatx4 acc0 = {0.f, 0.f, 0.f, 0.f};
        floatx4 acc1 = {0.f, 0.f, 0.f, 0.f};
        const int brow  = n0 + l15;
        const int kbase = quad * 8;
        #pragma unroll
        for (int kc = 0; kc < 16; kc += 2) {
            bf16x8 bh0 = *(const bf16x8*)&Hs_hi[brow][kc * 32 + kbase];
            bf16x8 bl0 = *(const bf16x8*)&Hs_lo[brow][kc * 32 + kbase];
            bf16x8 bh1 = *(const bf16x8*)&Hs_hi[brow][(kc + 1) * 32 + kbase];
            bf16x8 bl1 = *(const bf16x8*)&Hs_lo[brow][(kc + 1) * 32 + kbase];
            acc0 = __builtin_amdgcn_mfma_f32_16x16x32_bf16(w_hi[kc],     bh0, acc0, 0, 0, 0);
            acc1 = __builtin_amdgcn_mfma_f32_16x16x32_bf16(w_hi[kc + 1], bh1, acc1, 0, 0, 0);
            acc0 = __builtin_amdgcn_mfma_f32_16x16x32_bf16(w_hi[kc],     bl0, acc0, 0, 0, 0);
            acc1 = __builtin_amdgcn_mfma_f32_16x16x32_bf16(w_hi[kc + 1], bl1, acc1, 0, 0, 0);
            acc0 = __builtin_amdgcn_mfma_f32_16x16x32_bf16(w_lo[kc],     bh0, acc0, 0, 0, 0);
            acc1 = __builtin_amdgcn_mfma_f32_16x16x32_bf16(w_lo[kc + 1], bh1, acc1, 0, 0, 0);
        }

        #pragma unroll
        for (int r = 0; r < 4; ++r)
            Gs[m0 + quad * 4 + r][n0 + l15] = acc0[r] + acc1[r];
        __syncthreads();

        // ---- fp32 elementwise update; pack + store ----
        {
            const float gi = Gs[j_u][b_u]      + xgi;
            const float gf = Gs[8 + j_u][b_u]  + xgf;
            const float gg = Gs[16 + j_u][b_u] + xgg;
            const float go = Gs[24 + j_u][b_u] + xgo;
            const float si = 1.f / (1.f + __expf(-gi));
            const float sf = 1.f / (1.f + __expf(-gf));
            const float tg = 2.f / (1.f + __expf(-2.f * gg)) - 1.f;
            const float so = 1.f / (1.f + __expf(-go));
            c_reg = sf * c_reg + si * tg;
            const float th = 2.f / (1.f + __expf(-2.f * c_reg)) - 1.f;
            const float hval = so * th;
            const size_t row = (size_t)(bt * 32 + b_u) * HH + j0 + j_u;
            const unsigned short hb = f2bf(hval);
            const unsigned short lb = f2bf(hval - bf2f(hb));
            const unsigned pk = ((unsigned)hb << 16) | (unsigned)lb;
            __hip_atomic_store(&hpack[(size_t)(t + 1) * (BB * HH) + row], pk,
                               __ATOMIC_RELAXED, __HIP_MEMORY_SCOPE_AGENT);
        }

        if (t != TT - 1) grid_barrier(slots, (unsigned)(gen_base + t + 1));
    }
}

// ---------------------------------------------------------------------------
// Classifier split-K partial GEMM on packed h (unchanged from R5)
// ---------------------------------------------------------------------------
__global__ __launch_bounds__(256) void cls_partial_kernel(
    const unsigned* __restrict__ A, const float* __restrict__ W,
    float* __restrict__ part)
{
    const int n0 = blockIdx.x * 64;
    const int s  = blockIdx.y;
    const int kbase = s * 2048;
    const int tid = threadIdx.x;
    __shared__ float As[32][68];
    __shared__ float Bs[32][68];
    const int tm = tid >> 4, tn = tid & 15;
    float acc[4][4] = {};

    for (int kt = 0; kt < 2048; kt += 32) {
        #pragma unroll
        for (int q = tid; q < 512; q += 256) {
            const int mm = q >> 3;
            const int kq = q & 7;
            uint4 v = *(const uint4*)&A[(size_t)mm * KFLAT + kbase + kt + kq * 4];
            As[kq*4+0][mm] = pk2f(v.x); As[kq*4+1][mm] = pk2f(v.y);
            As[kq*4+2][mm] = pk2f(v.z); As[kq*4+3][mm] = pk2f(v.w);
            float4 w = *(const float4*)&W[(size_t)(n0 + mm) * KFLAT + kbase + kt + kq * 4];
            Bs[kq*4+0][mm] = w.x; Bs[kq*4+1][mm] = w.y;
            Bs[kq*4+2][mm] = w.z; Bs[kq*4+3][mm] = w.w;
        }
        __syncthreads();
        #pragma unroll
        for (int k = 0; k < 32; ++k) {
            float4 a = *(const float4*)&As[k][tm * 4];
            float4 b = *(const float4*)&Bs[k][tn * 4];
            acc[0][0] += a.x*b.x; acc[0][1] += a.x*b.y; acc[0][2] += a.x*b.z; acc[0][3] += a.x*b.w;
            acc[1][0] += a.y*b.x; acc[1][1] += a.y*b.y; acc[1][2] += a.y*b.z; acc[1][3] += a.y*b.w;
            acc[2][0] += a.z*b.x; acc[2][1] += a.z*b.y; acc[2][2] += a.z*b.z; acc[2][3] += a.z*b.w;
            acc[3][0] += a.w*b.x; acc[3][1] += a.w*b.y; acc[3][2] += a.w*b.z; acc[3][3] += a.w*b.w;
        }
        __syncthreads();
    }
    #pragma unroll
    for (int i = 0; i < 4; ++i) {
        const int m = tm * 4 + i;
        #pragma unroll
        for (int j = 0; j < 4; ++j) {
            part[((size_t)s * 64 + m) * 512 + n0 + tn * 4 + j] = acc[i][j];
        }
    }
}

// ---------------------------------------------------------------------------
// Classifier finish (unchanged)
// ---------------------------------------------------------------------------
__global__ __launch_bounds__(256) void cls_final_kernel(
    const float* __restrict__ part, const float* __restrict__ b1,
    const float* __restrict__ w2, const float* __restrict__ b2,
    float* __restrict__ out)
{
    const int t = blockIdx.x;
    __shared__ float hm[512];
    for (int n = threadIdx.x; n < 512; n += 256) {
        float sacc = b1[n];
        for (int sl = 0; sl < 32; ++sl)
            sacc += part[((size_t)sl * 64 + t) * 512 + n];
        hm[n] = fmaxf(sacc, 0.f);
    }
    __syncthreads();
    if (threadIdx.x < NCC) {
        float sacc = b2[threadIdx.x];
        const float* wr = w2 + (size_t)threadIdx.x * 512;
        for (int n = 0; n < 512; ++n) sacc += hm[n] * wr[n];
        out[t * NCC + threadIdx.x] = sacc;
    }
}

// ---------------------------------------------------------------------------
extern "C" void kernel_launch(void* const* d_in, const int* in_sizes, int n_in,
                              void* d_out, int out_size, void* d_ws, size_t ws_size,
                              hipStream_t stream)
{
    const float* x     = (const float*)d_in[0];
    const float* w_ih0 = (const float*)d_in[1];
    const float* w_hh0 = (const float*)d_in[2];
    const float* b_ih0 = (const float*)d_in[3];
    const float* b_hh0 = (const float*)d_in[4];
    const float* w_ih1 = (const float*)d_in[5];
    const float* w_hh1 = (const float*)d_in[6];
    const float* b_ih1 = (const float*)d_in[7];
    const float* b_hh1 = (const float*)d_in[8];
    const float* w1    = (const float*)d_in[9];
    const float* b1    = (const float*)d_in[10];
    const float* w2    = (const float*)d_in[11];
    const float* b2    = (const float*)d_in[12];
    float* out = (float*)d_out;

    // Workspace layout (~98.3 MB)
    float*    ws    = (float*)d_ws;
    float*    xg    = ws;                                        // [8192,2048] 64 MB
    unsigned* hpack = (unsigned*)(xg + (size_t)8192 * 2048);     // [65][128][512] 16.25 MB
    float*    part  = (float*)(hpack + (size_t)65 * BB * HH);    // [32][64][512] 4 MB
    unsigned* xpk   = (unsigned*)(part + (size_t)32 * 64 * 512); // [8192][256] 8 MB
    unsigned* w0pk  = xpk + (size_t)8192 * IND;                  // [2048][256] 2 MB
    unsigned* w1pk  = w0pk + (size_t)GG * IND;                   // [2048][512] 4 MB
    unsigned* slots = w1pk + (size_t)GG * HH;                    // 1025 u32

    hipMemsetAsync(hpack, 0, (size_t)BB * HH * sizeof(unsigned), stream);  // t=0 block
    hipMemsetAsync(slots, 0, 1028 * sizeof(unsigned), stream);

    // ---- pack inputs to split-bf16 ----
    pack_split_kernel<<<1024, 256, 0, stream>>>(x, xpk, 8192 * IND);
    pack_split_kernel<<<512,  256, 0, stream>>>(w_ih0, w0pk, GG * IND);
    pack_split_kernel<<<1024, 256, 0, stream>>>(w_ih1, w1pk, GG * HH);

    // ---- layer 0 ----
    gemm_pk_mfma<<<dim3(8192 / 128, GG / 128), 256, 0, stream>>>(
        xpk, w0pk, b_ih0, b_hh0, xg, IND, GG);
    lstm_persistent<<<256, 256, 0, stream>>>(xg, w_hh0, hpack, slots, 0);

    // ---- layer 1 (A = packed h of layer 0, blocks 1..64) ----
    gemm_pk_mfma<<<dim3(8192 / 128, GG / 128), 256, 0, stream>>>(
        hpack + (size_t)BB * HH, w1pk, b_ih1, b_hh1, xg, HH, GG);
    lstm_persistent<<<256, 256, 0, stream>>>(xg, w_hh1, hpack, slots, 64);

    // ---- classifier (packed h of layer 1, blocks 1..64) ----
    cls_partial_kernel<<<dim3(512 / 64, 32), 256, 0, stream>>>(
        hpack + (size_t)BB * HH, w1, part);
    cls_final_kernel<<<64, 256, 0, stream>>>(part, b1, w2, b2, out);
}

// Round 7
// 1259.821 us; speedup vs baseline: 7.0148x; 1.0166x over previous
//
#include <hip/hip_runtime.h>

// Problem constants (reference: T=64 time steps, B=SEQ=128 batch, IN=256, H=512)
#define TT 64
#define BB 128
#define IND 256
#define HH 512
#define GG 2048      // 4*H
#define NCC 10
#define KFLAT 65536  // SEQ*H
#define HP2 520      // bf16 LDS row stride in lstm kernel (512 + 8)
#define SP 36        // GEMM LDS short stride (32 data + 4 pad)

typedef __attribute__((ext_vector_type(8))) short bf16x8;   // 8 bf16 in 4 VGPRs
typedef __attribute__((ext_vector_type(4))) float floatx4;  // MFMA accumulator

__device__ __forceinline__ unsigned short f2bf(float x) {   // RNE round to bf16
    unsigned u = __builtin_bit_cast(unsigned, x);
    u += 0x7fffu + ((u >> 16) & 1u);
    return (unsigned short)(u >> 16);
}
__device__ __forceinline__ float bf2f(unsigned short h) {
    unsigned u = ((unsigned)h) << 16;
    return __builtin_bit_cast(float, u);
}
// packed u32 (hi<<16 | lo) -> fp32 (hi + lo)
__device__ __forceinline__ float pk2f(unsigned u) {
    float hi = __builtin_bit_cast(float, u & 0xffff0000u);
    float lo = __builtin_bit_cast(float, u << 16);
    return hi + lo;
}

// ---------------------------------------------------------------------------
// Elementwise: fp32 -> packed split-bf16 (hi<<16 | lo)
// ---------------------------------------------------------------------------
__global__ __launch_bounds__(256) void pack_split_kernel(
    const float* __restrict__ src, unsigned* __restrict__ dst, int n)
{
    for (int i = blockIdx.x * 256 + threadIdx.x; i < n; i += gridDim.x * 256) {
        float f = src[i];
        unsigned short hb = f2bf(f);
        unsigned short lb = f2bf(f - bf2f(hb));
        dst[i] = ((unsigned)hb << 16) | lb;
    }
}

// ---------------------------------------------------------------------------
// MFMA GEMM on packed split-bf16 (proven R6). 128x128 tile, 4 waves,
// 3 MFMA per k-chunk (hi*hi + hi*lo + lo*hi).
// ---------------------------------------------------------------------------
__global__ __launch_bounds__(256) void gemm_pk_mfma(
    const unsigned* __restrict__ A, const unsigned* __restrict__ W,
    const float* __restrict__ b0, const float* __restrict__ b1,
    float* __restrict__ C, int K, int N)
{
    __shared__ short Ahi[128][SP], Alo[128][SP], Whi[128][SP], Wlo[128][SP];

    const int tid  = threadIdx.x;
    const int lane = tid & 63;
    const int wv   = tid >> 6;
    const int wm   = (wv & 1) * 64;
    const int wn   = (wv >> 1) * 64;
    const int l15  = lane & 15;
    const int quad = lane >> 4;
    const int m0   = blockIdx.x * 128;
    const int n0   = blockIdx.y * 128;

    floatx4 acc[4][4];
    #pragma unroll
    for (int i = 0; i < 4; ++i)
        #pragma unroll
        for (int j = 0; j < 4; ++j)
            acc[i][j] = (floatx4){0.f, 0.f, 0.f, 0.f};

    for (int kc = 0; kc < K; kc += 32) {
        #pragma unroll
        for (int it = 0; it < 4; ++it) {
            const int lin = it * 256 + tid;
            const int row = lin >> 3;
            const int c4  = (lin & 7) * 4;
            uint4 va = *(const uint4*)&A[(size_t)(m0 + row) * K + kc + c4];
            uint2 ah, al;
            ah.x = (va.x >> 16) | (va.y & 0xffff0000u);
            ah.y = (va.z >> 16) | (va.w & 0xffff0000u);
            al.x = (va.x & 0xffffu) | (va.y << 16);
            al.y = (va.z & 0xffffu) | (va.w << 16);
            *(uint2*)&Ahi[row][c4] = ah;
            *(uint2*)&Alo[row][c4] = al;
            uint4 vw = *(const uint4*)&W[(size_t)(n0 + row) * K + kc + c4];
            uint2 wh, wl;
            wh.x = (vw.x >> 16) | (vw.y & 0xffff0000u);
            wh.y = (vw.z >> 16) | (vw.w & 0xffff0000u);
            wl.x = (vw.x & 0xffffu) | (vw.y << 16);
            wl.y = (vw.z & 0xffffu) | (vw.w << 16);
            *(uint2*)&Whi[row][c4] = wh;
            *(uint2*)&Wlo[row][c4] = wl;
        }
        __syncthreads();

        bf16x8 afh[4], afl[4], bfh[4], bfl[4];
        #pragma unroll
        for (int i = 0; i < 4; ++i) {
            afh[i] = *(const bf16x8*)&Ahi[wm + i * 16 + l15][quad * 8];
            afl[i] = *(const bf16x8*)&Alo[wm + i * 16 + l15][quad * 8];
            bfh[i] = *(const bf16x8*)&Whi[wn + i * 16 + l15][quad * 8];
            bfl[i] = *(const bf16x8*)&Wlo[wn + i * 16 + l15][quad * 8];
        }
        #pragma unroll
        for (int i = 0; i < 4; ++i)
            #pragma unroll
            for (int j = 0; j < 4; ++j) {
                acc[i][j] = __builtin_amdgcn_mfma_f32_16x16x32_bf16(afh[i], bfh[j], acc[i][j], 0, 0, 0);
                acc[i][j] = __builtin_amdgcn_mfma_f32_16x16x32_bf16(afh[i], bfl[j], acc[i][j], 0, 0, 0);
                acc[i][j] = __builtin_amdgcn_mfma_f32_16x16x32_bf16(afl[i], bfh[j], acc[i][j], 0, 0, 0);
            }
        __syncthreads();
    }

    #pragma unroll
    for (int i = 0; i < 4; ++i) {
        #pragma unroll
        for (int j = 0; j < 4; ++j) {
            const int n = n0 + wn + j * 16 + l15;
            const float bias = b0[n] + b1[n];
            #pragma unroll
            for (int r = 0; r < 4; ++r) {
                const int m = m0 + wm + i * 16 + quad * 4 + r;
                C[(size_t)m * N + n] = acc[i][j][r] + bias;
            }
        }
    }
}

// ---------------------------------------------------------------------------
// Persistent LSTM layer, split-bf16 MFMA, per-bt-group sync.
// Grid = 256 WGs x 256 thr, 1 WG/CU. WG (bt,j0): batches [bt*32,+32) x
// hidden units [j0,+8) x 4 gates. h produced/consumed ONLY within the 64-WG
// group sharing bt -> 4 independent symmetric sweep barriers (no publish
// flag): every WG's wave 0 polls its group's 64 arrival slots directly.
// All atomics relaxed agent scope (IF$ point, no L2 invalidates).
// ---------------------------------------------------------------------------
__global__ __launch_bounds__(256, 1) void lstm_persistent(
    const float* __restrict__ xg,     // [T][B][4H] (biases already added)
    const float* __restrict__ w_hh,   // [4H][H] fp32
    unsigned* __restrict__ hpack,     // [T+1][B][H] packed, block 0 zeroed
    unsigned* __restrict__ slots,     // [4 groups][64 slots x 4 stride]
    int gen_base)
{
    __shared__ short Hs_hi[32][HP2];
    __shared__ short Hs_lo[32][HP2];
    __shared__ float Gs[32][36];      // stride 36: <=2-way banks on r/w (free)

    const int tid  = threadIdx.x;
    const int lane = tid & 63;
    const int wv   = tid >> 6;
    const int bt   = blockIdx.x & 3;
    const int j0   = (blockIdx.x >> 2) * 8;

    const int m0   = (wv & 1) * 16;
    const int n0   = (wv >> 1) * 16;
    const int l15  = lane & 15;
    const int quad = lane >> 4;

    unsigned* gslots = slots + (size_t)bt * 256;   // this group's 64 slots
    const int  myslot = blockIdx.x >> 2;           // 0..63 within group

    // ---- preload W_hh fragments (split hi/lo bf16), A-operand layout ----
    bf16x8 w_hi[16], w_lo[16];
    {
        const int m  = m0 + l15;
        const int g  = m >> 3, jj = m & 7;
        const float* wrow = w_hh + (size_t)(g * HH + j0 + jj) * HH + quad * 8;
        #pragma unroll
        for (int kc = 0; kc < 16; ++kc) {
            float f[8];
            *(float4*)&f[0] = *(const float4*)&wrow[kc * 32];
            *(float4*)&f[4] = *(const float4*)&wrow[kc * 32 + 4];
            bf16x8 vh, vl;
            #pragma unroll
            for (int j = 0; j < 8; ++j) {
                unsigned short hb = f2bf(f[j]);
                vh[j] = (short)hb;
                vl[j] = (short)f2bf(f[j] - bf2f(hb));
            }
            w_hi[kc] = vh; w_lo[kc] = vl;
        }
    }

    // update-phase mapping: consecutive lanes -> consecutive hidden units
    // (32B-contiguous xg loads / h stores: 8 lines/instr instead of 64)
    const int j_u = tid & 7;
    const int b_u = tid >> 3;          // 0..31

    float c_reg = 0.f;

    for (int t = 0; t < TT; ++t) {
        const unsigned* hsrc = hpack + (size_t)t * (BB * HH) + (size_t)bt * 32 * HH;

        // xg loads (independent of h; overlap the h IF$ latency)
        const float* xt = xg + (size_t)t * (BB * GG)
                        + (size_t)(bt * 32 + b_u) * GG + j0 + j_u;
        const float xgi = xt[0];
        const float xgf = xt[HH];
        const float xgg = xt[2 * HH];
        const float xgo = xt[3 * HH];

        // ---- stage h: coherent 8B loads of packed u32s -> shift-unpack ----
        #pragma unroll
        for (int p = 0; p < 8; ++p) {
            const int idx = p * 2048 + tid * 8;
            const int bb = idx >> 9, kk = idx & 511;
            const unsigned long long* src = (const unsigned long long*)&hsrc[idx];
            unsigned long long q0 = __hip_atomic_load(src + 0, __ATOMIC_RELAXED, __HIP_MEMORY_SCOPE_AGENT);
            unsigned long long q1 = __hip_atomic_load(src + 1, __ATOMIC_RELAXED, __HIP_MEMORY_SCOPE_AGENT);
            unsigned long long q2 = __hip_atomic_load(src + 2, __ATOMIC_RELAXED, __HIP_MEMORY_SCOPE_AGENT);
            unsigned long long q3 = __hip_atomic_load(src + 3, __ATOMIC_RELAXED, __HIP_MEMORY_SCOPE_AGENT);
            unsigned c0 = (unsigned)q0, c1 = (unsigned)(q0 >> 32);
            unsigned c2 = (unsigned)q1, c3 = (unsigned)(q1 >> 32);
            unsigned c4 = (unsigned)q2, c5 = (unsigned)(q2 >> 32);
            unsigned c6 = (unsigned)q3, c7 = (unsigned)(q3 >> 32);
            uint4 hiv, lov;
            hiv.x = (c0 >> 16) | (c1 & 0xffff0000u);
            hiv.y = (c2 >> 16) | (c3 & 0xffff0000u);
            hiv.z = (c4 >> 16) | (c5 & 0xffff0000u);
            hiv.w = (c6 >> 16) | (c7 & 0xffff0000u);
            lov.x = (c0 & 0xffffu) | (c1 << 16);
            lov.y = (c2 & 0xffffu) | (c3 << 16);
            lov.z = (c4 & 0xffffu) | (c5 << 16);
            lov.w = (c6 & 0xffffu) | (c7 << 16);
            *(uint4*)&Hs_hi[bb][kk] = hiv;
            *(uint4*)&Hs_lo[bb][kk] = lov;
        }
        __syncthreads();

        // ---- MFMA mainloop: D[32 gates][32 batches] += Whh . h^T ----
        floatx4 acc0 = {0.f, 0.f, 0.f, 0.f};
        floatx4 acc1 = {0.f, 0.f, 0.f, 0.f};
        const int brow  = n0 + l15;
        const int kbase = quad * 8;
        #pragma unroll
        for (int kc = 0; kc < 16; kc += 2) {
            bf16x8 bh0 = *(const bf16x8*)&Hs_hi[brow][kc * 32 + kbase];
            bf16x8 bl0 = *(const bf16x8*)&Hs_lo[brow][kc * 32 + kbase];
            bf16x8 bh1 = *(const bf16x8*)&Hs_hi[brow][(kc + 1) * 32 + kbase];
            bf16x8 bl1 = *(const bf16x8*)&Hs_lo[brow][(kc + 1) * 32 + kbase];
            acc0 = __builtin_amdgcn_mfma_f32_16x16x32_bf16(w_hi[kc],     bh0, acc0, 0, 0, 0);
            acc1 = __builtin_amdgcn_mfma_f32_16x16x32_bf16(w_hi[kc + 1], bh1, acc1, 0, 0, 0);
            acc0 = __builtin_amdgcn_mfma_f32_16x16x32_bf16(w_hi[kc],     bl0, acc0, 0, 0, 0);
            acc1 = __builtin_amdgcn_mfma_f32_16x16x32_bf16(w_hi[kc + 1], bl1, acc1, 0, 0, 0);
            acc0 = __builtin_amdgcn_mfma_f32_16x16x32_bf16(w_lo[kc],     bh0, acc0, 0, 0, 0);
            acc1 = __builtin_amdgcn_mfma_f32_16x16x32_bf16(w_lo[kc + 1], bh1, acc1, 0, 0, 0);
        }

        // ---- exchange gate preacts (C/D: col=lane&15 batch, row=quad*4+r) ----
        #pragma unroll
        for (int r = 0; r < 4; ++r)
            Gs[m0 + quad * 4 + r][n0 + l15] = acc0[r] + acc1[r];
        __syncthreads();

        // ---- fp32 elementwise update; pack + coalesced store ----
        {
            const float gi = Gs[j_u][b_u]      + xgi;
            const float gf = Gs[8 + j_u][b_u]  + xgf;
            const float gg = Gs[16 + j_u][b_u] + xgg;
            const float go = Gs[24 + j_u][b_u] + xgo;
            const float si = 1.f / (1.f + __expf(-gi));
            const float sf = 1.f / (1.f + __expf(-gf));
            const float tg = 2.f / (1.f + __expf(-2.f * gg)) - 1.f;
            const float so = 1.f / (1.f + __expf(-go));
            c_reg = sf * c_reg + si * tg;
            const float th = 2.f / (1.f + __expf(-2.f * c_reg)) - 1.f;
            const float hval = so * th;
            const size_t row = (size_t)(bt * 32 + b_u) * HH + j0 + j_u;
            const unsigned short hb = f2bf(hval);
            const unsigned short lb = f2bf(hval - bf2f(hb));
            const unsigned pk = ((unsigned)hb << 16) | (unsigned)lb;
            __hip_atomic_store(&hpack[(size_t)(t + 1) * (BB * HH) + row], pk,
                               __ATOMIC_RELAXED, __HIP_MEMORY_SCOPE_AGENT);
        }

        // ---- symmetric per-group barrier (64 WGs, no publish round-trip) ----
        if (t != TT - 1) {
            const unsigned gen = (unsigned)(gen_base + t + 1);
            __syncthreads();   // h stores drained (vmcnt0 before s_barrier)
            if (tid < 64) {
                if (tid == 0)
                    __hip_atomic_store(&gslots[myslot * 4], gen, __ATOMIC_RELAXED,
                                       __HIP_MEMORY_SCOPE_AGENT);
                const unsigned* my = &gslots[tid * 4];
                for (;;) {
                    unsigned v = __hip_atomic_load(my, __ATOMIC_RELAXED,
                                                   __HIP_MEMORY_SCOPE_AGENT);
                    if (__all((int)(v >= gen))) break;
                    __builtin_amdgcn_s_sleep(1);
                }
            }
            __syncthreads();
            asm volatile("" ::: "memory");
        }
    }
}

// ---------------------------------------------------------------------------
// Classifier split-K partial GEMM on packed h (unchanged)
// ---------------------------------------------------------------------------
__global__ __launch_bounds__(256) void cls_partial_kernel(
    const unsigned* __restrict__ A, const float* __restrict__ W,
    float* __restrict__ part)
{
    const int n0 = blockIdx.x * 64;
    const int s  = blockIdx.y;
    const int kbase = s * 2048;
    const int tid = threadIdx.x;
    __shared__ float As[32][68];
    __shared__ float Bs[32][68];
    const int tm = tid >> 4, tn = tid & 15;
    float acc[4][4] = {};

    for (int kt = 0; kt < 2048; kt += 32) {
        #pragma unroll
        for (int q = tid; q < 512; q += 256) {
            const int mm = q >> 3;
            const int kq = q & 7;
            uint4 v = *(const uint4*)&A[(size_t)mm * KFLAT + kbase + kt + kq * 4];
            As[kq*4+0][mm] = pk2f(v.x); As[kq*4+1][mm] = pk2f(v.y);
            As[kq*4+2][mm] = pk2f(v.z); As[kq*4+3][mm] = pk2f(v.w);
            float4 w = *(const float4*)&W[(size_t)(n0 + mm) * KFLAT + kbase + kt + kq * 4];
            Bs[kq*4+0][mm] = w.x; Bs[kq*4+1][mm] = w.y;
            Bs[kq*4+2][mm] = w.z; Bs[kq*4+3][mm] = w.w;
        }
        __syncthreads();
        #pragma unroll
        for (int k = 0; k < 32; ++k) {
            float4 a = *(const float4*)&As[k][tm * 4];
            float4 b = *(const float4*)&Bs[k][tn * 4];
            acc[0][0] += a.x*b.x; acc[0][1] += a.x*b.y; acc[0][2] += a.x*b.z; acc[0][3] += a.x*b.w;
            acc[1][0] += a.y*b.x; acc[1][1] += a.y*b.y; acc[1][2] += a.y*b.z; acc[1][3] += a.y*b.w;
            acc[2][0] += a.z*b.x; acc[2][1] += a.z*b.y; acc[2][2] += a.z*b.z; acc[2][3] += a.z*b.w;
            acc[3][0] += a.w*b.x; acc[3][1] += a.w*b.y; acc[3][2] += a.w*b.z; acc[3][3] += a.w*b.w;
        }
        __syncthreads();
    }
    #pragma unroll
    for (int i = 0; i < 4; ++i) {
        const int m = tm * 4 + i;
        #pragma unroll
        for (int j = 0; j < 4; ++j) {
            part[((size_t)s * 64 + m) * 512 + n0 + tn * 4 + j] = acc[i][j];
        }
    }
}

// ---------------------------------------------------------------------------
// Classifier finish (unchanged)
// ---------------------------------------------------------------------------
__global__ __launch_bounds__(256) void cls_final_kernel(
    const float* __restrict__ part, const float* __restrict__ b1,
    const float* __restrict__ w2, const float* __restrict__ b2,
    float* __restrict__ out)
{
    const int t = blockIdx.x;
    __shared__ float hm[512];
    for (int n = threadIdx.x; n < 512; n += 256) {
        float sacc = b1[n];
        for (int sl = 0; sl < 32; ++sl)
            sacc += part[((size_t)sl * 64 + t) * 512 + n];
        hm[n] = fmaxf(sacc, 0.f);
    }
    __syncthreads();
    if (threadIdx.x < NCC) {
        float sacc = b2[threadIdx.x];
        const float* wr = w2 + (size_t)threadIdx.x * 512;
        for (int n = 0; n < 512; ++n) sacc += hm[n] * wr[n];
        out[t * NCC + threadIdx.x] = sacc;
    }
}

// ---------------------------------------------------------------------------
extern "C" void kernel_launch(void* const* d_in, const int* in_sizes, int n_in,
                              void* d_out, int out_size, void* d_ws, size_t ws_size,
                              hipStream_t stream)
{
    const float* x     = (const float*)d_in[0];
    const float* w_ih0 = (const float*)d_in[1];
    const float* w_hh0 = (const float*)d_in[2];
    const float* b_ih0 = (const float*)d_in[3];
    const float* b_hh0 = (const float*)d_in[4];
    const float* w_ih1 = (const float*)d_in[5];
    const float* w_hh1 = (const float*)d_in[6];
    const float* b_ih1 = (const float*)d_in[7];
    const float* b_hh1 = (const float*)d_in[8];
    const float* w1    = (const float*)d_in[9];
    const float* b1    = (const float*)d_in[10];
    const float* w2    = (const float*)d_in[11];
    const float* b2    = (const float*)d_in[12];
    float* out = (float*)d_out;

    // Workspace layout (~98.3 MB)
    float*    ws    = (float*)d_ws;
    float*    xg    = ws;                                        // [8192,2048] 64 MB
    unsigned* hpack = (unsigned*)(xg + (size_t)8192 * 2048);     // [65][128][512] 16.25 MB
    float*    part  = (float*)(hpack + (size_t)65 * BB * HH);    // [32][64][512] 4 MB
    unsigned* xpk   = (unsigned*)(part + (size_t)32 * 64 * 512); // [8192][256] 8 MB
    unsigned* w0pk  = xpk + (size_t)8192 * IND;                  // [2048][256] 2 MB
    unsigned* w1pk  = w0pk + (size_t)GG * IND;                   // [2048][512] 4 MB
    unsigned* slots = w1pk + (size_t)GG * HH;                    // [4][64x4] u32 = 4 KB

    hipMemsetAsync(hpack, 0, (size_t)BB * HH * sizeof(unsigned), stream);  // t=0 block
    hipMemsetAsync(slots, 0, 1024 * sizeof(unsigned), stream);

    // ---- pack inputs to split-bf16 ----
    pack_split_kernel<<<1024, 256, 0, stream>>>(x, xpk, 8192 * IND);
    pack_split_kernel<<<512,  256, 0, stream>>>(w_ih0, w0pk, GG * IND);
    pack_split_kernel<<<1024, 256, 0, stream>>>(w_ih1, w1pk, GG * HH);

    // ---- layer 0 ----
    gemm_pk_mfma<<<dim3(8192 / 128, GG / 128), 256, 0, stream>>>(
        xpk, w0pk, b_ih0, b_hh0, xg, IND, GG);
    lstm_persistent<<<256, 256, 0, stream>>>(xg, w_hh0, hpack, slots, 0);

    // ---- layer 1 (A = packed h of layer 0, blocks 1..64) ----
    gemm_pk_mfma<<<dim3(8192 / 128, GG / 128), 256, 0, stream>>>(
        hpack + (size_t)BB * HH, w1pk, b_ih1, b_hh1, xg, HH, GG);
    lstm_persistent<<<256, 256, 0, stream>>>(xg, w_hh1, hpack, slots, 64);

    // ---- classifier (packed h of layer 1, blocks 1..64) ----
    cls_partial_kernel<<<dim3(512 / 64, 32), 256, 0, stream>>>(
        hpack + (size_t)BB * HH, w1, part);
    cls_final_kernel<<<64, 256, 0, stream>>>(part, b1, w2, b2, out);
}

// Round 8
// 1159.768 us; speedup vs baseline: 7.6199x; 1.0863x over previous
//
#include <hip/hip_runtime.h>

// Problem constants (reference: T=64 time steps, B=SEQ=128 batch, IN=256, H=512)
#define TT 64
#define BB 128
#define IND 256
#define HH 512
#define GG 2048      // 4*H
#define NCC 10
#define KFLAT 65536  // SEQ*H
#define HP2 520      // bf16 LDS row stride in lstm kernel (512 + 8)
#define SP 36        // GEMM LDS short stride (32 data + 4 pad)

typedef __attribute__((ext_vector_type(8))) short bf16x8;   // 8 bf16 in 4 VGPRs
typedef __attribute__((ext_vector_type(4))) float floatx4;  // MFMA accumulator

__device__ __forceinline__ unsigned short f2bf(float x) {   // RNE round to bf16
    unsigned u = __builtin_bit_cast(unsigned, x);
    u += 0x7fffu + ((u >> 16) & 1u);
    return (unsigned short)(u >> 16);
}
__device__ __forceinline__ float bf2f(unsigned short h) {
    unsigned u = ((unsigned)h) << 16;
    return __builtin_bit_cast(float, u);
}
// packed u32 (hi<<16 | lo) -> fp32 (hi + lo)
__device__ __forceinline__ float pk2f(unsigned u) {
    float hi = __builtin_bit_cast(float, u & 0xffff0000u);
    float lo = __builtin_bit_cast(float, u << 16);
    return hi + lo;
}

// ---------------------------------------------------------------------------
// Elementwise: fp32 -> packed split-bf16 (hi<<16 | lo), full-precision lo
// (inputs/weights only -- h cells use the tagged variant inside the lstm)
// ---------------------------------------------------------------------------
__global__ __launch_bounds__(256) void pack_split_kernel(
    const float* __restrict__ src, unsigned* __restrict__ dst, int n)
{
    for (int i = blockIdx.x * 256 + threadIdx.x; i < n; i += gridDim.x * 256) {
        float f = src[i];
        unsigned short hb = f2bf(f);
        unsigned short lb = f2bf(f - bf2f(hb));
        dst[i] = ((unsigned)hb << 16) | lb;
    }
}

// ---------------------------------------------------------------------------
// MFMA GEMM on packed split-bf16 (proven R6). 128x128 tile, 4 waves,
// 3 MFMA per k-chunk (hi*hi + hi*lo + lo*hi).
// ---------------------------------------------------------------------------
__global__ __launch_bounds__(256) void gemm_pk_mfma(
    const unsigned* __restrict__ A, const unsigned* __restrict__ W,
    const float* __restrict__ b0, const float* __restrict__ b1,
    float* __restrict__ C, int K, int N)
{
    __shared__ short Ahi[128][SP], Alo[128][SP], Whi[128][SP], Wlo[128][SP];

    const int tid  = threadIdx.x;
    const int lane = tid & 63;
    const int wv   = tid >> 6;
    const int wm   = (wv & 1) * 64;
    const int wn   = (wv >> 1) * 64;
    const int l15  = lane & 15;
    const int quad = lane >> 4;
    const int m0   = blockIdx.x * 128;
    const int n0   = blockIdx.y * 128;

    floatx4 acc[4][4];
    #pragma unroll
    for (int i = 0; i < 4; ++i)
        #pragma unroll
        for (int j = 0; j < 4; ++j)
            acc[i][j] = (floatx4){0.f, 0.f, 0.f, 0.f};

    for (int kc = 0; kc < K; kc += 32) {
        #pragma unroll
        for (int it = 0; it < 4; ++it) {
            const int lin = it * 256 + tid;
            const int row = lin >> 3;
            const int c4  = (lin & 7) * 4;
            uint4 va = *(const uint4*)&A[(size_t)(m0 + row) * K + kc + c4];
            uint2 ah, al;
            ah.x = (va.x >> 16) | (va.y & 0xffff0000u);
            ah.y = (va.z >> 16) | (va.w & 0xffff0000u);
            al.x = (va.x & 0xffffu) | (va.y << 16);
            al.y = (va.z & 0xffffu) | (va.w << 16);
            *(uint2*)&Ahi[row][c4] = ah;
            *(uint2*)&Alo[row][c4] = al;
            uint4 vw = *(const uint4*)&W[(size_t)(n0 + row) * K + kc + c4];
            uint2 wh, wl;
            wh.x = (vw.x >> 16) | (vw.y & 0xffff0000u);
            wh.y = (vw.z >> 16) | (vw.w & 0xffff0000u);
            wl.x = (vw.x & 0xffffu) | (vw.y << 16);
            wl.y = (vw.z & 0xffffu) | (vw.w << 16);
            *(uint2*)&Whi[row][c4] = wh;
            *(uint2*)&Wlo[row][c4] = wl;
        }
        __syncthreads();

        bf16x8 afh[4], afl[4], bfh[4], bfl[4];
        #pragma unroll
        for (int i = 0; i < 4; ++i) {
            afh[i] = *(const bf16x8*)&Ahi[wm + i * 16 + l15][quad * 8];
            afl[i] = *(const bf16x8*)&Alo[wm + i * 16 + l15][quad * 8];
            bfh[i] = *(const bf16x8*)&Whi[wn + i * 16 + l15][quad * 8];
            bfl[i] = *(const bf16x8*)&Wlo[wn + i * 16 + l15][quad * 8];
        }
        #pragma unroll
        for (int i = 0; i < 4; ++i)
            #pragma unroll
            for (int j = 0; j < 4; ++j) {
                acc[i][j] = __builtin_amdgcn_mfma_f32_16x16x32_bf16(afh[i], bfh[j], acc[i][j], 0, 0, 0);
                acc[i][j] = __builtin_amdgcn_mfma_f32_16x16x32_bf16(afh[i], bfl[j], acc[i][j], 0, 0, 0);
                acc[i][j] = __builtin_amdgcn_mfma_f32_16x16x32_bf16(afl[i], bfh[j], acc[i][j], 0, 0, 0);
            }
        __syncthreads();
    }

    #pragma unroll
    for (int i = 0; i < 4; ++i) {
        #pragma unroll
        for (int j = 0; j < 4; ++j) {
            const int n = n0 + wn + j * 16 + l15;
            const float bias = b0[n] + b1[n];
            #pragma unroll
            for (int r = 0; r < 4; ++r) {
                const int m = m0 + wm + i * 16 + quad * 4 + r;
                C[(size_t)m * N + n] = acc[i][j][r] + bias;
            }
        }
    }
}

// ---------------------------------------------------------------------------
// Same GEMM but A = TAGGED h cells (hi16 | lo12 | tag4): mask tag nibble out
// of the lo plane during staging. W = full-precision packed (w1pk).
// ---------------------------------------------------------------------------
__global__ __launch_bounds__(256) void gemm_hpk_mfma(
    const unsigned* __restrict__ A, const unsigned* __restrict__ W,
    const float* __restrict__ b0, const float* __restrict__ b1,
    float* __restrict__ C, int K, int N)
{
    __shared__ short Ahi[128][SP], Alo[128][SP], Whi[128][SP], Wlo[128][SP];

    const int tid  = threadIdx.x;
    const int lane = tid & 63;
    const int wv   = tid >> 6;
    const int wm   = (wv & 1) * 64;
    const int wn   = (wv >> 1) * 64;
    const int l15  = lane & 15;
    const int quad = lane >> 4;
    const int m0   = blockIdx.x * 128;
    const int n0   = blockIdx.y * 128;

    floatx4 acc[4][4];
    #pragma unroll
    for (int i = 0; i < 4; ++i)
        #pragma unroll
        for (int j = 0; j < 4; ++j)
            acc[i][j] = (floatx4){0.f, 0.f, 0.f, 0.f};

    for (int kc = 0; kc < K; kc += 32) {
        #pragma unroll
        for (int it = 0; it < 4; ++it) {
            const int lin = it * 256 + tid;
            const int row = lin >> 3;
            const int c4  = (lin & 7) * 4;
            uint4 va = *(const uint4*)&A[(size_t)(m0 + row) * K + kc + c4];
            uint2 ah, al;
            ah.x = (va.x >> 16) | (va.y & 0xffff0000u);
            ah.y = (va.z >> 16) | (va.w & 0xffff0000u);
            al.x = (va.x & 0xFFF0u) | ((va.y & 0xFFF0u) << 16);
            al.y = (va.z & 0xFFF0u) | ((va.w & 0xFFF0u) << 16);
            *(uint2*)&Ahi[row][c4] = ah;
            *(uint2*)&Alo[row][c4] = al;
            uint4 vw = *(const uint4*)&W[(size_t)(n0 + row) * K + kc + c4];
            uint2 wh, wl;
            wh.x = (vw.x >> 16) | (vw.y & 0xffff0000u);
            wh.y = (vw.z >> 16) | (vw.w & 0xffff0000u);
            wl.x = (vw.x & 0xffffu) | (vw.y << 16);
            wl.y = (vw.z & 0xffffu) | (vw.w << 16);
            *(uint2*)&Whi[row][c4] = wh;
            *(uint2*)&Wlo[row][c4] = wl;
        }
        __syncthreads();

        bf16x8 afh[4], afl[4], bfh[4], bfl[4];
        #pragma unroll
        for (int i = 0; i < 4; ++i) {
            afh[i] = *(const bf16x8*)&Ahi[wm + i * 16 + l15][quad * 8];
            afl[i] = *(const bf16x8*)&Alo[wm + i * 16 + l15][quad * 8];
            bfh[i] = *(const bf16x8*)&Whi[wn + i * 16 + l15][quad * 8];
            bfl[i] = *(const bf16x8*)&Wlo[wn + i * 16 + l15][quad * 8];
        }
        #pragma unroll
        for (int i = 0; i < 4; ++i)
            #pragma unroll
            for (int j = 0; j < 4; ++j) {
                acc[i][j] = __builtin_amdgcn_mfma_f32_16x16x32_bf16(afh[i], bfh[j], acc[i][j], 0, 0, 0);
                acc[i][j] = __builtin_amdgcn_mfma_f32_16x16x32_bf16(afh[i], bfl[j], acc[i][j], 0, 0, 0);
                acc[i][j] = __builtin_amdgcn_mfma_f32_16x16x32_bf16(afl[i], bfh[j], acc[i][j], 0, 0, 0);
            }
        __syncthreads();
    }

    #pragma unroll
    for (int i = 0; i < 4; ++i) {
        #pragma unroll
        for (int j = 0; j < 4; ++j) {
            const int n = n0 + wn + j * 16 + l15;
            const float bias = b0[n] + b1[n];
            #pragma unroll
            for (int r = 0; r < 4; ++r) {
                const int m = m0 + wm + i * 16 + quad * 4 + r;
                C[(size_t)m * N + n] = acc[i][j][r] + bias;
            }
        }
    }
}

// ---------------------------------------------------------------------------
// Stage 8 tagged h-cells (4x8B coherent loads) into LDS hi/lo planes.
// Returns nonzero if any cell's tag nibble != exp (caller retries).
// ---------------------------------------------------------------------------
__device__ __forceinline__ unsigned stage8(
    const unsigned long long* __restrict__ src, int bb, int kk, unsigned exp,
    short (*Hs_hi)[HP2], short (*Hs_lo)[HP2])
{
    unsigned long long q0 = __hip_atomic_load(src + 0, __ATOMIC_RELAXED, __HIP_MEMORY_SCOPE_AGENT);
    unsigned long long q1 = __hip_atomic_load(src + 1, __ATOMIC_RELAXED, __HIP_MEMORY_SCOPE_AGENT);
    unsigned long long q2 = __hip_atomic_load(src + 2, __ATOMIC_RELAXED, __HIP_MEMORY_SCOPE_AGENT);
    unsigned long long q3 = __hip_atomic_load(src + 3, __ATOMIC_RELAXED, __HIP_MEMORY_SCOPE_AGENT);
    unsigned c0 = (unsigned)q0, c1 = (unsigned)(q0 >> 32);
    unsigned c2 = (unsigned)q1, c3 = (unsigned)(q1 >> 32);
    unsigned c4 = (unsigned)q2, c5 = (unsigned)(q2 >> 32);
    unsigned c6 = (unsigned)q3, c7 = (unsigned)(q3 >> 32);
    unsigned bad = ((c0 ^ exp) | (c1 ^ exp) | (c2 ^ exp) | (c3 ^ exp)
                  | (c4 ^ exp) | (c5 ^ exp) | (c6 ^ exp) | (c7 ^ exp)) & 0xFu;
    uint4 hiv, lov;
    hiv.x = (c0 >> 16) | (c1 & 0xffff0000u);
    hiv.y = (c2 >> 16) | (c3 & 0xffff0000u);
    hiv.z = (c4 >> 16) | (c5 & 0xffff0000u);
    hiv.w = (c6 >> 16) | (c7 & 0xffff0000u);
    lov.x = (c0 & 0xFFF0u) | ((c1 & 0xFFF0u) << 16);
    lov.y = (c2 & 0xFFF0u) | ((c3 & 0xFFF0u) << 16);
    lov.z = (c4 & 0xFFF0u) | ((c5 & 0xFFF0u) << 16);
    lov.w = (c6 & 0xFFF0u) | ((c7 & 0xFFF0u) << 16);
    *(uint4*)&Hs_hi[bb][kk] = hiv;
    *(uint4*)&Hs_lo[bb][kk] = lov;
    return bad;
}

// ---------------------------------------------------------------------------
// Persistent LSTM layer, split-bf16 MFMA, TAGGED-DATA synchronization.
// No grid barrier: h cells carry a 4-bit generation tag (gen % 9) in the lo
// word's low nibble. Producers fire-and-forget sc1 stores; consumers bulk-
// load + tag-check + retry only missed groups. Poison nibble 0xA and stale
// cross-layer tags (differ by 64%9=1) never match. Block 0 memset = tag 0.
// ---------------------------------------------------------------------------
__global__ __launch_bounds__(256, 1) void lstm_persistent(
    const float* __restrict__ xg,     // [T][B][4H] (biases already added)
    const float* __restrict__ w_hh,   // [4H][H] fp32
    unsigned* __restrict__ hpack,     // [T+1][B][H] tagged cells, block 0 zeroed
    int gen_base)
{
    __shared__ short Hs_hi[32][HP2];
    __shared__ short Hs_lo[32][HP2];
    __shared__ float Gs[32][36];

    const int tid  = threadIdx.x;
    const int lane = tid & 63;
    const int wv   = tid >> 6;
    const int bt   = blockIdx.x & 3;
    const int j0   = (blockIdx.x >> 2) * 8;

    const int m0   = (wv & 1) * 16;
    const int n0   = (wv >> 1) * 16;
    const int l15  = lane & 15;
    const int quad = lane >> 4;

    // ---- preload W_hh fragments (split hi/lo bf16), A-operand layout ----
    bf16x8 w_hi[16], w_lo[16];
    {
        const int m  = m0 + l15;
        const int g  = m >> 3, jj = m & 7;
        const float* wrow = w_hh + (size_t)(g * HH + j0 + jj) * HH + quad * 8;
        #pragma unroll
        for (int kc = 0; kc < 16; ++kc) {
            float f[8];
            *(float4*)&f[0] = *(const float4*)&wrow[kc * 32];
            *(float4*)&f[4] = *(const float4*)&wrow[kc * 32 + 4];
            bf16x8 vh, vl;
            #pragma unroll
            for (int j = 0; j < 8; ++j) {
                unsigned short hb = f2bf(f[j]);
                vh[j] = (short)hb;
                vl[j] = (short)f2bf(f[j] - bf2f(hb));
            }
            w_hi[kc] = vh; w_lo[kc] = vl;
        }
    }

    // update-phase mapping: consecutive lanes -> consecutive hidden units
    const int j_u = tid & 7;
    const int b_u = tid >> 3;          // 0..31

    float c_reg = 0.f;

    for (int t = 0; t < TT; ++t) {
        const unsigned long long* hsrc64 = (const unsigned long long*)
            (hpack + (size_t)t * (BB * HH) + (size_t)bt * 32 * HH);
        const unsigned exp = (t == 0) ? 0u : ((unsigned)(gen_base + t)) % 9u;

        // xg loads (independent of h; overlap the poll latency)
        const float* xt = xg + (size_t)t * (BB * GG)
                        + (size_t)(bt * 32 + b_u) * GG + j0 + j_u;
        const float xgi = xt[0];
        const float xgf = xt[HH];
        const float xgg = xt[2 * HH];
        const float xgo = xt[3 * HH];

        // ---- stage h: pipelined bulk pass + tag-check, retry missed groups ----
        unsigned miss = 0;
        #pragma unroll
        for (int p = 0; p < 8; ++p) {
            const int idx = p * 2048 + tid * 8;
            unsigned bad = stage8(hsrc64 + (idx >> 1), idx >> 9, idx & 511,
                                  exp, Hs_hi, Hs_lo);
            miss |= (bad ? 1u : 0u) << p;
        }
        while (miss) {
            #pragma unroll
            for (int p = 0; p < 8; ++p) {
                if (miss & (1u << p)) {
                    const int idx = p * 2048 + tid * 8;
                    unsigned bad = stage8(hsrc64 + (idx >> 1), idx >> 9, idx & 511,
                                          exp, Hs_hi, Hs_lo);
                    if (!bad) miss &= ~(1u << p);
                }
            }
        }
        __syncthreads();

        // ---- MFMA mainloop: D[32 gates][32 batches] += Whh . h^T ----
        floatx4 acc0 = {0.f, 0.f, 0.f, 0.f};
        floatx4 acc1 = {0.f, 0.f, 0.f, 0.f};
        const int brow  = n0 + l15;
        const int kbase = quad * 8;
        #pragma unroll
        for (int kc = 0; kc < 16; kc += 2) {
            bf16x8 bh0 = *(const bf16x8*)&Hs_hi[brow][kc * 32 + kbase];
            bf16x8 bl0 = *(const bf16x8*)&Hs_lo[brow][kc * 32 + kbase];
            bf16x8 bh1 = *(const bf16x8*)&Hs_hi[brow][(kc + 1) * 32 + kbase];
            bf16x8 bl1 = *(const bf16x8*)&Hs_lo[brow][(kc + 1) * 32 + kbase];
            acc0 = __builtin_amdgcn_mfma_f32_16x16x32_bf16(w_hi[kc],     bh0, acc0, 0, 0, 0);
            acc1 = __builtin_amdgcn_mfma_f32_16x16x32_bf16(w_hi[kc + 1], bh1, acc1, 0, 0, 0);
            acc0 = __builtin_amdgcn_mfma_f32_16x16x32_bf16(w_hi[kc],     bl0, acc0, 0, 0, 0);
            acc1 = __builtin_amdgcn_mfma_f32_16x16x32_bf16(w_hi[kc + 1], bl1, acc1, 0, 0, 0);
            acc0 = __builtin_amdgcn_mfma_f32_16x16x32_bf16(w_lo[kc],     bh0, acc0, 0, 0, 0);
            acc1 = __builtin_amdgcn_mfma_f32_16x16x32_bf16(w_lo[kc + 1], bh1, acc1, 0, 0, 0);
        }

        // ---- exchange gate preacts (C/D: col=lane&15 batch, row=quad*4+r) ----
        #pragma unroll
        for (int r = 0; r < 4; ++r)
            Gs[m0 + quad * 4 + r][n0 + l15] = acc0[r] + acc1[r];
        __syncthreads();

        // ---- fp32 elementwise update; tagged pack + fire-and-forget store ----
        {
            const float gi = Gs[j_u][b_u]      + xgi;
            const float gf = Gs[8 + j_u][b_u]  + xgf;
            const float gg = Gs[16 + j_u][b_u] + xgg;
            const float go = Gs[24 + j_u][b_u] + xgo;
            const float si = 1.f / (1.f + __expf(-gi));
            const float sf = 1.f / (1.f + __expf(-gf));
            const float tg = 2.f / (1.f + __expf(-2.f * gg)) - 1.f;
            const float so = 1.f / (1.f + __expf(-go));
            c_reg = sf * c_reg + si * tg;
            const float th = 2.f / (1.f + __expf(-2.f * c_reg)) - 1.f;
            const float hval = so * th;
            const size_t row = (size_t)(bt * 32 + b_u) * HH + j0 + j_u;
            const unsigned tag = ((unsigned)(gen_base + t + 1)) % 9u;
            const unsigned short hb = f2bf(hval);
            const unsigned short lb = f2bf(hval - bf2f(hb));
            const unsigned pk = ((unsigned)hb << 16) | ((unsigned)lb & 0xFFF0u) | tag;
            __hip_atomic_store(&hpack[(size_t)(t + 1) * (BB * HH) + row], pk,
                               __ATOMIC_RELAXED, __HIP_MEMORY_SCOPE_AGENT);
        }
        // loop: next staging writes Hs only after this sync's predecessors
        // (all MFMA reads of Hs completed before the Gs sync above)
    }
}

// ---------------------------------------------------------------------------
// Classifier split-K partial GEMM on tagged h cells (mask tag nibble)
// ---------------------------------------------------------------------------
__global__ __launch_bounds__(256) void cls_partial_kernel(
    const unsigned* __restrict__ A, const float* __restrict__ W,
    float* __restrict__ part)
{
    const int n0 = blockIdx.x * 64;
    const int s  = blockIdx.y;
    const int kbase = s * 2048;
    const int tid = threadIdx.x;
    __shared__ float As[32][68];
    __shared__ float Bs[32][68];
    const int tm = tid >> 4, tn = tid & 15;
    float acc[4][4] = {};

    for (int kt = 0; kt < 2048; kt += 32) {
        #pragma unroll
        for (int q = tid; q < 512; q += 256) {
            const int mm = q >> 3;
            const int kq = q & 7;
            uint4 v = *(const uint4*)&A[(size_t)mm * KFLAT + kbase + kt + kq * 4];
            As[kq*4+0][mm] = pk2f(v.x & 0xFFFFFFF0u); As[kq*4+1][mm] = pk2f(v.y & 0xFFFFFFF0u);
            As[kq*4+2][mm] = pk2f(v.z & 0xFFFFFFF0u); As[kq*4+3][mm] = pk2f(v.w & 0xFFFFFFF0u);
            float4 w = *(const float4*)&W[(size_t)(n0 + mm) * KFLAT + kbase + kt + kq * 4];
            Bs[kq*4+0][mm] = w.x; Bs[kq*4+1][mm] = w.y;
            Bs[kq*4+2][mm] = w.z; Bs[kq*4+3][mm] = w.w;
        }
        __syncthreads();
        #pragma unroll
        for (int k = 0; k < 32; ++k) {
            float4 a = *(const float4*)&As[k][tm * 4];
            float4 b = *(const float4*)&Bs[k][tn * 4];
            acc[0][0] += a.x*b.x; acc[0][1] += a.x*b.y; acc[0][2] += a.x*b.z; acc[0][3] += a.x*b.w;
            acc[1][0] += a.y*b.x; acc[1][1] += a.y*b.y; acc[1][2] += a.y*b.z; acc[1][3] += a.y*b.w;
            acc[2][0] += a.z*b.x; acc[2][1] += a.z*b.y; acc[2][2] += a.z*b.z; acc[2][3] += a.z*b.w;
            acc[3][0] += a.w*b.x; acc[3][1] += a.w*b.y; acc[3][2] += a.w*b.z; acc[3][3] += a.w*b.w;
        }
        __syncthreads();
    }
    #pragma unroll
    for (int i = 0; i < 4; ++i) {
        const int m = tm * 4 + i;
        #pragma unroll
        for (int j = 0; j < 4; ++j) {
            part[((size_t)s * 64 + m) * 512 + n0 + tn * 4 + j] = acc[i][j];
        }
    }
}

// ---------------------------------------------------------------------------
// Classifier finish (unchanged)
// ---------------------------------------------------------------------------
__global__ __launch_bounds__(256) void cls_final_kernel(
    const float* __restrict__ part, const float* __restrict__ b1,
    const float* __restrict__ w2, const float* __restrict__ b2,
    float* __restrict__ out)
{
    const int t = blockIdx.x;
    __shared__ float hm[512];
    for (int n = threadIdx.x; n < 512; n += 256) {
        float sacc = b1[n];
        for (int sl = 0; sl < 32; ++sl)
            sacc += part[((size_t)sl * 64 + t) * 512 + n];
        hm[n] = fmaxf(sacc, 0.f);
    }
    __syncthreads();
    if (threadIdx.x < NCC) {
        float sacc = b2[threadIdx.x];
        const float* wr = w2 + (size_t)threadIdx.x * 512;
        for (int n = 0; n < 512; ++n) sacc += hm[n] * wr[n];
        out[t * NCC + threadIdx.x] = sacc;
    }
}

// ---------------------------------------------------------------------------
extern "C" void kernel_launch(void* const* d_in, const int* in_sizes, int n_in,
                              void* d_out, int out_size, void* d_ws, size_t ws_size,
                              hipStream_t stream)
{
    const float* x     = (const float*)d_in[0];
    const float* w_ih0 = (const float*)d_in[1];
    const float* w_hh0 = (const float*)d_in[2];
    const float* b_ih0 = (const float*)d_in[3];
    const float* b_hh0 = (const float*)d_in[4];
    const float* w_ih1 = (const float*)d_in[5];
    const float* w_hh1 = (const float*)d_in[6];
    const float* b_ih1 = (const float*)d_in[7];
    const float* b_hh1 = (const float*)d_in[8];
    const float* w1    = (const float*)d_in[9];
    const float* b1    = (const float*)d_in[10];
    const float* w2    = (const float*)d_in[11];
    const float* b2    = (const float*)d_in[12];
    float* out = (float*)d_out;

    // Workspace layout (~98.3 MB, proven)
    float*    ws    = (float*)d_ws;
    float*    xg    = ws;                                        // [8192,2048] 64 MB
    unsigned* hpack = (unsigned*)(xg + (size_t)8192 * 2048);     // [65][128][512] 16.25 MB
    float*    part  = (float*)(hpack + (size_t)65 * BB * HH);    // [32][64][512] 4 MB
    unsigned* xpk   = (unsigned*)(part + (size_t)32 * 64 * 512); // [8192][256] 8 MB
    unsigned* w0pk  = xpk + (size_t)8192 * IND;                  // [2048][256] 2 MB
    unsigned* w1pk  = w0pk + (size_t)GG * IND;                   // [2048][512] 4 MB

    // t=0 block: zeros with tag nibble 0 (= gen 0)
    hipMemsetAsync(hpack, 0, (size_t)BB * HH * sizeof(unsigned), stream);

    // ---- pack inputs to split-bf16 ----
    pack_split_kernel<<<1024, 256, 0, stream>>>(x, xpk, 8192 * IND);
    pack_split_kernel<<<512,  256, 0, stream>>>(w_ih0, w0pk, GG * IND);
    pack_split_kernel<<<1024, 256, 0, stream>>>(w_ih1, w1pk, GG * HH);

    // ---- layer 0 ----
    gemm_pk_mfma<<<dim3(8192 / 128, GG / 128), 256, 0, stream>>>(
        xpk, w0pk, b_ih0, b_hh0, xg, IND, GG);
    lstm_persistent<<<256, 256, 0, stream>>>(xg, w_hh0, hpack, 0);

    // ---- layer 1 (A = tagged h of layer 0, blocks 1..64) ----
    gemm_hpk_mfma<<<dim3(8192 / 128, GG / 128), 256, 0, stream>>>(
        hpack + (size_t)BB * HH, w1pk, b_ih1, b_hh1, xg, HH, GG);
    lstm_persistent<<<256, 256, 0, stream>>>(xg, w_hh1, hpack, 64);

    // ---- classifier (tagged h of layer 1, blocks 1..64) ----
    cls_partial_kernel<<<dim3(512 / 64, 32), 256, 0, stream>>>(
        hpack + (size_t)BB * HH, w1, part);
    cls_final_kernel<<<64, 256, 0, stream>>>(part, b1, w2, b2, out);
}

// Round 9
// 1078.481 us; speedup vs baseline: 8.1943x; 1.0754x over previous
//
#include <hip/hip_runtime.h>

// Problem constants (reference: T=64 time steps, B=SEQ=128 batch, IN=256, H=512)
#define TT 64
#define BB 128
#define IND 256
#define HH 512
#define GG 2048      // 4*H
#define NCC 10
#define KFLAT 65536  // SEQ*H
#define HP2 520      // bf16 LDS row stride (512 + 8)
#define SP 36        // GEMM LDS short stride

typedef __attribute__((ext_vector_type(8))) short bf16x8;
typedef __attribute__((ext_vector_type(4))) float floatx4;

__device__ __forceinline__ unsigned short f2bf(float x) {   // RNE round to bf16
    unsigned u = __builtin_bit_cast(unsigned, x);
    u += 0x7fffu + ((u >> 16) & 1u);
    return (unsigned short)(u >> 16);
}
__device__ __forceinline__ float bf2f(unsigned short h) {
    unsigned u = ((unsigned)h) << 16;
    return __builtin_bit_cast(float, u);
}
__device__ __forceinline__ float pk2f(unsigned u) {
    float hi = __builtin_bit_cast(float, u & 0xffff0000u);
    float lo = __builtin_bit_cast(float, u << 16);
    return hi + lo;
}

// ---------------------------------------------------------------------------
// Elementwise: fp32 -> packed split-bf16 (hi<<16 | lo)
// ---------------------------------------------------------------------------
__global__ __launch_bounds__(256) void pack_split_kernel(
    const float* __restrict__ src, unsigned* __restrict__ dst, int n)
{
    for (int i = blockIdx.x * 256 + threadIdx.x; i < n; i += gridDim.x * 256) {
        float f = src[i];
        unsigned short hb = f2bf(f);
        unsigned short lb = f2bf(f - bf2f(hb));
        dst[i] = ((unsigned)hb << 16) | lb;
    }
}

// ---------------------------------------------------------------------------
// MFMA GEMM on packed split-bf16 (proven R6): layer-0 input transform only.
// ---------------------------------------------------------------------------
__global__ __launch_bounds__(256) void gemm_pk_mfma(
    const unsigned* __restrict__ A, const unsigned* __restrict__ W,
    const float* __restrict__ b0, const float* __restrict__ b1,
    float* __restrict__ C, int K, int N)
{
    __shared__ short Ahi[128][SP], Alo[128][SP], Whi[128][SP], Wlo[128][SP];

    const int tid  = threadIdx.x;
    const int lane = tid & 63;
    const int wv   = tid >> 6;
    const int wm   = (wv & 1) * 64;
    const int wn   = (wv >> 1) * 64;
    const int l15  = lane & 15;
    const int quad = lane >> 4;
    const int m0   = blockIdx.x * 128;
    const int n0   = blockIdx.y * 128;

    floatx4 acc[4][4];
    #pragma unroll
    for (int i = 0; i < 4; ++i)
        #pragma unroll
        for (int j = 0; j < 4; ++j)
            acc[i][j] = (floatx4){0.f, 0.f, 0.f, 0.f};

    for (int kc = 0; kc < K; kc += 32) {
        #pragma unroll
        for (int it = 0; it < 4; ++it) {
            const int lin = it * 256 + tid;
            const int row = lin >> 3;
            const int c4  = (lin & 7) * 4;
            uint4 va = *(const uint4*)&A[(size_t)(m0 + row) * K + kc + c4];
            uint2 ah, al;
            ah.x = (va.x >> 16) | (va.y & 0xffff0000u);
            ah.y = (va.z >> 16) | (va.w & 0xffff0000u);
            al.x = (va.x & 0xffffu) | (va.y << 16);
            al.y = (va.z & 0xffffu) | (va.w << 16);
            *(uint2*)&Ahi[row][c4] = ah;
            *(uint2*)&Alo[row][c4] = al;
            uint4 vw = *(const uint4*)&W[(size_t)(n0 + row) * K + kc + c4];
            uint2 wh, wl;
            wh.x = (vw.x >> 16) | (vw.y & 0xffff0000u);
            wh.y = (vw.z >> 16) | (vw.w & 0xffff0000u);
            wl.x = (vw.x & 0xffffu) | (vw.y << 16);
            wl.y = (vw.z & 0xffffu) | (vw.w << 16);
            *(uint2*)&Whi[row][c4] = wh;
            *(uint2*)&Wlo[row][c4] = wl;
        }
        __syncthreads();

        bf16x8 afh[4], afl[4], bfh[4], bfl[4];
        #pragma unroll
        for (int i = 0; i < 4; ++i) {
            afh[i] = *(const bf16x8*)&Ahi[wm + i * 16 + l15][quad * 8];
            afl[i] = *(const bf16x8*)&Alo[wm + i * 16 + l15][quad * 8];
            bfh[i] = *(const bf16x8*)&Whi[wn + i * 16 + l15][quad * 8];
            bfl[i] = *(const bf16x8*)&Wlo[wn + i * 16 + l15][quad * 8];
        }
        #pragma unroll
        for (int i = 0; i < 4; ++i)
            #pragma unroll
            for (int j = 0; j < 4; ++j) {
                acc[i][j] = __builtin_amdgcn_mfma_f32_16x16x32_bf16(afh[i], bfh[j], acc[i][j], 0, 0, 0);
                acc[i][j] = __builtin_amdgcn_mfma_f32_16x16x32_bf16(afh[i], bfl[j], acc[i][j], 0, 0, 0);
                acc[i][j] = __builtin_amdgcn_mfma_f32_16x16x32_bf16(afl[i], bfh[j], acc[i][j], 0, 0, 0);
            }
        __syncthreads();
    }

    #pragma unroll
    for (int i = 0; i < 4; ++i) {
        #pragma unroll
        for (int j = 0; j < 4; ++j) {
            const int n = n0 + wn + j * 16 + l15;
            const float bias = b0[n] + b1[n];
            #pragma unroll
            for (int r = 0; r < 4; ++r) {
                const int m = m0 + wm + i * 16 + quad * 4 + r;
                C[(size_t)m * N + n] = acc[i][j][r] + bias;
            }
        }
    }
}

// ---------------------------------------------------------------------------
// Stage 8 tagged h-cells into LDS hi/lo planes; returns nonzero on tag miss.
// ---------------------------------------------------------------------------
__device__ __forceinline__ unsigned stage8(
    const unsigned long long* __restrict__ src, int bb, int kk, unsigned exp,
    short (*Hs_hi)[HP2], short (*Hs_lo)[HP2])
{
    unsigned long long q0 = __hip_atomic_load(src + 0, __ATOMIC_RELAXED, __HIP_MEMORY_SCOPE_AGENT);
    unsigned long long q1 = __hip_atomic_load(src + 1, __ATOMIC_RELAXED, __HIP_MEMORY_SCOPE_AGENT);
    unsigned long long q2 = __hip_atomic_load(src + 2, __ATOMIC_RELAXED, __HIP_MEMORY_SCOPE_AGENT);
    unsigned long long q3 = __hip_atomic_load(src + 3, __ATOMIC_RELAXED, __HIP_MEMORY_SCOPE_AGENT);
    unsigned c0 = (unsigned)q0, c1 = (unsigned)(q0 >> 32);
    unsigned c2 = (unsigned)q1, c3 = (unsigned)(q1 >> 32);
    unsigned c4 = (unsigned)q2, c5 = (unsigned)(q2 >> 32);
    unsigned c6 = (unsigned)q3, c7 = (unsigned)(q3 >> 32);
    unsigned bad = ((c0 ^ exp) | (c1 ^ exp) | (c2 ^ exp) | (c3 ^ exp)
                  | (c4 ^ exp) | (c5 ^ exp) | (c6 ^ exp) | (c7 ^ exp)) & 0xFu;
    uint4 hiv, lov;
    hiv.x = (c0 >> 16) | (c1 & 0xffff0000u);
    hiv.y = (c2 >> 16) | (c3 & 0xffff0000u);
    hiv.z = (c4 >> 16) | (c5 & 0xffff0000u);
    hiv.w = (c6 >> 16) | (c7 & 0xffff0000u);
    lov.x = (c0 & 0xFFF0u) | ((c1 & 0xFFF0u) << 16);
    lov.y = (c2 & 0xFFF0u) | ((c3 & 0xFFF0u) << 16);
    lov.z = (c4 & 0xFFF0u) | ((c5 & 0xFFF0u) << 16);
    lov.w = (c6 & 0xFFF0u) | ((c7 & 0xFFF0u) << 16);
    *(uint4*)&Hs_hi[bb][kk] = hiv;
    *(uint4*)&Hs_lo[bb][kk] = lov;
    return bad;
}

// ---------------------------------------------------------------------------
// FUSED two-layer persistent LSTM, tag-synchronized wave pipeline.
// Blocks 0..127 = layer 0; blocks 128..255 = layer 1 (runs ~1 step behind,
// self-timed by tags -- no barriers anywhere). WG (bt, j0): batches
// [bt*32,+32) x 16 hidden units x 4 gates (wave g = gate g). Layer-1 WGs
// compute BOTH matmuls per step: h0[t]@W_ih1^T + h1[t-1]@W_hh1^T, weights
// in registers (2x128 VGPRs of frags). Tag = gen%9 in lo nibble; 0xA
// (harness poison) and 0xF (scrub) never match.
// ---------------------------------------------------------------------------
__global__ __launch_bounds__(256, 1) void lstm_fused(
    const float* __restrict__ xg,     // [T][B][4H] layer-0 (biases included)
    const float* __restrict__ w_hh0,  // [4H][H] fp32
    const float* __restrict__ w_ih1,  // [4H][H] fp32
    const float* __restrict__ w_hh1,  // [4H][H] fp32
    const float* __restrict__ b_ih1, const float* __restrict__ b_hh1,
    unsigned* __restrict__ hpack0,    // [T+1][B][H] tagged, block 0 zeroed
    unsigned* __restrict__ hpack1)    // [T+1][B][H] tagged, scrubbed 0xFF, block 0 zeroed
{
    __shared__ short Ra_hi[32][HP2], Ra_lo[32][HP2];   // recurrent h tile
    __shared__ short Xa_hi[32][HP2], Xa_lo[32][HP2];   // layer-1 input h0 tile
    __shared__ float Gs[64][33];

    const int tid  = threadIdx.x;
    const int lane = tid & 63;
    const int wv   = tid >> 6;               // wave = gate 0..3
    const bool isB = blockIdx.x >= 128;
    const int blk  = blockIdx.x & 127;
    const int bt   = blk & 3;
    const int j0   = (blk >> 2) * 16;        // 16-unit slice
    const int l15  = lane & 15;
    const int quad = lane >> 4;

    // ---- preload recurrent-weight frags (16 rows: gate wv, units j0+l15) ----
    bf16x8 wa_hi[16], wa_lo[16], wx_hi[16], wx_lo[16];
    {
        const float* wsrc = isB ? w_hh1 : w_hh0;
        const float* wrow = wsrc + (size_t)(wv * HH + j0 + l15) * HH + quad * 8;
        #pragma unroll
        for (int kc = 0; kc < 16; ++kc) {
            float f[8];
            *(float4*)&f[0] = *(const float4*)&wrow[kc * 32];
            *(float4*)&f[4] = *(const float4*)&wrow[kc * 32 + 4];
            bf16x8 vh, vl;
            #pragma unroll
            for (int j = 0; j < 8; ++j) {
                unsigned short hb = f2bf(f[j]);
                vh[j] = (short)hb;
                vl[j] = (short)f2bf(f[j] - bf2f(hb));
            }
            wa_hi[kc] = vh; wa_lo[kc] = vl;
        }
        if (isB) {
            const float* xrow = w_ih1 + (size_t)(wv * HH + j0 + l15) * HH + quad * 8;
            #pragma unroll
            for (int kc = 0; kc < 16; ++kc) {
                float f[8];
                *(float4*)&f[0] = *(const float4*)&xrow[kc * 32];
                *(float4*)&f[4] = *(const float4*)&xrow[kc * 32 + 4];
                bf16x8 vh, vl;
                #pragma unroll
                for (int j = 0; j < 8; ++j) {
                    unsigned short hb = f2bf(f[j]);
                    vh[j] = (short)hb;
                    vl[j] = (short)f2bf(f[j] - bf2f(hb));
                }
                wx_hi[kc] = vh; wx_lo[kc] = vl;
            }
        }
    }

    // update-phase roles: (j_u, bu) and (j_u, bu+16)
    const int j_u = tid & 15;
    const int bu  = tid >> 4;          // 0..15
    float bias_i = 0.f, bias_f = 0.f, bias_g = 0.f, bias_o = 0.f;
    if (isB) {
        bias_i = b_ih1[j0 + j_u]            + b_hh1[j0 + j_u];
        bias_f = b_ih1[HH + j0 + j_u]       + b_hh1[HH + j0 + j_u];
        bias_g = b_ih1[2 * HH + j0 + j_u]   + b_hh1[2 * HH + j0 + j_u];
        bias_o = b_ih1[3 * HH + j0 + j_u]   + b_hh1[3 * HH + j0 + j_u];
    }

    unsigned* hp_rec = isB ? hpack1 : hpack0;
    float c0 = 0.f, c1 = 0.f;

    for (int t = 0; t < TT; ++t) {
        const unsigned long long* rec64 = (const unsigned long long*)
            (hp_rec + (size_t)t * (BB * HH) + (size_t)bt * 32 * HH);
        const unsigned long long* inp64 = (const unsigned long long*)
            (hpack0 + (size_t)(t + 1) * (BB * HH) + (size_t)bt * 32 * HH);
        const unsigned expR = (unsigned)t % 9u;
        const unsigned expX = (unsigned)(t + 1) % 9u;

        // layer-0: xg loads (overlap poll latency)
        float xgv[2][4];
        if (!isB) {
            #pragma unroll
            for (int ccell = 0; ccell < 2; ++ccell) {
                const int b = bu + ccell * 16;
                const float* base = xg + (size_t)t * (BB * GG)
                                  + (size_t)(bt * 32 + b) * GG + j0 + j_u;
                xgv[ccell][0] = base[0];
                xgv[ccell][1] = base[HH];
                xgv[ccell][2] = base[2 * HH];
                xgv[ccell][3] = base[3 * HH];
            }
        }

        // ---- stage tiles with tag-retry ----
        unsigned missR = 0, missX = 0;
        #pragma unroll
        for (int p = 0; p < 8; ++p) {
            const int idx = p * 2048 + tid * 8;
            unsigned bad = stage8(rec64 + (idx >> 1), idx >> 9, idx & 511,
                                  expR, Ra_hi, Ra_lo);
            missR |= (bad ? 1u : 0u) << p;
        }
        if (isB) {
            #pragma unroll
            for (int p = 0; p < 8; ++p) {
                const int idx = p * 2048 + tid * 8;
                unsigned bad = stage8(inp64 + (idx >> 1), idx >> 9, idx & 511,
                                      expX, Xa_hi, Xa_lo);
                missX |= (bad ? 1u : 0u) << p;
            }
        }
        while (missR | missX) {
            #pragma unroll
            for (int p = 0; p < 8; ++p) {
                if (missR & (1u << p)) {
                    const int idx = p * 2048 + tid * 8;
                    if (!stage8(rec64 + (idx >> 1), idx >> 9, idx & 511,
                                expR, Ra_hi, Ra_lo)) missR &= ~(1u << p);
                }
                if (missX & (1u << p)) {
                    const int idx = p * 2048 + tid * 8;
                    if (!stage8(inp64 + (idx >> 1), idx >> 9, idx & 511,
                                expX, Xa_hi, Xa_lo)) missX &= ~(1u << p);
                }
            }
        }
        __syncthreads();

        // ---- MFMA: acc[half] = Wrec . h_rec (+ Wih1 . h0 for layer 1) ----
        floatx4 aR0 = {0.f,0.f,0.f,0.f}, aR1 = {0.f,0.f,0.f,0.f};
        floatx4 aX0 = {0.f,0.f,0.f,0.f}, aX1 = {0.f,0.f,0.f,0.f};
        #pragma unroll
        for (int kc = 0; kc < 16; ++kc) {
            const int off = kc * 32 + quad * 8;
            bf16x8 r0h = *(const bf16x8*)&Ra_hi[l15][off];
            bf16x8 r0l = *(const bf16x8*)&Ra_lo[l15][off];
            bf16x8 r1h = *(const bf16x8*)&Ra_hi[16 + l15][off];
            bf16x8 r1l = *(const bf16x8*)&Ra_lo[16 + l15][off];
            aR0 = __builtin_amdgcn_mfma_f32_16x16x32_bf16(wa_hi[kc], r0h, aR0, 0, 0, 0);
            aR1 = __builtin_amdgcn_mfma_f32_16x16x32_bf16(wa_hi[kc], r1h, aR1, 0, 0, 0);
            aR0 = __builtin_amdgcn_mfma_f32_16x16x32_bf16(wa_hi[kc], r0l, aR0, 0, 0, 0);
            aR1 = __builtin_amdgcn_mfma_f32_16x16x32_bf16(wa_hi[kc], r1l, aR1, 0, 0, 0);
            aR0 = __builtin_amdgcn_mfma_f32_16x16x32_bf16(wa_lo[kc], r0h, aR0, 0, 0, 0);
            aR1 = __builtin_amdgcn_mfma_f32_16x16x32_bf16(wa_lo[kc], r1h, aR1, 0, 0, 0);
            if (isB) {
                bf16x8 x0h = *(const bf16x8*)&Xa_hi[l15][off];
                bf16x8 x0l = *(const bf16x8*)&Xa_lo[l15][off];
                bf16x8 x1h = *(const bf16x8*)&Xa_hi[16 + l15][off];
                bf16x8 x1l = *(const bf16x8*)&Xa_lo[16 + l15][off];
                aX0 = __builtin_amdgcn_mfma_f32_16x16x32_bf16(wx_hi[kc], x0h, aX0, 0, 0, 0);
                aX1 = __builtin_amdgcn_mfma_f32_16x16x32_bf16(wx_hi[kc], x1h, aX1, 0, 0, 0);
                aX0 = __builtin_amdgcn_mfma_f32_16x16x32_bf16(wx_hi[kc], x0l, aX0, 0, 0, 0);
                aX1 = __builtin_amdgcn_mfma_f32_16x16x32_bf16(wx_hi[kc], x1l, aX1, 0, 0, 0);
                aX0 = __builtin_amdgcn_mfma_f32_16x16x32_bf16(wx_lo[kc], x0h, aX0, 0, 0, 0);
                aX1 = __builtin_amdgcn_mfma_f32_16x16x32_bf16(wx_lo[kc], x1h, aX1, 0, 0, 0);
            }
        }

        // ---- exchange preacts: rows = gate*16 + unit(quad*4+r) ----
        #pragma unroll
        for (int r = 0; r < 4; ++r) {
            Gs[wv * 16 + quad * 4 + r][l15]      = aR0[r] + aX0[r];
            Gs[wv * 16 + quad * 4 + r][16 + l15] = aR1[r] + aX1[r];
        }
        __syncthreads();

        // ---- elementwise update for 2 cells; tagged fire-and-forget store ----
        const unsigned tag = (unsigned)(t + 1) % 9u;
        #pragma unroll
        for (int ccell = 0; ccell < 2; ++ccell) {
            const int b = bu + ccell * 16;
            float gi = Gs[j_u][b],      gf = Gs[16 + j_u][b];
            float gg = Gs[32 + j_u][b], go = Gs[48 + j_u][b];
            if (isB) { gi += bias_i; gf += bias_f; gg += bias_g; go += bias_o; }
            else     { gi += xgv[ccell][0]; gf += xgv[ccell][1];
                       gg += xgv[ccell][2]; go += xgv[ccell][3]; }
            const float si = 1.f / (1.f + __expf(-gi));
            const float sf = 1.f / (1.f + __expf(-gf));
            const float tg = 2.f / (1.f + __expf(-2.f * gg)) - 1.f;
            const float so = 1.f / (1.f + __expf(-go));
            float& cr = ccell ? c1 : c0;
            cr = sf * cr + si * tg;
            const float th = 2.f / (1.f + __expf(-2.f * cr)) - 1.f;
            const float hval = so * th;
            const unsigned short hb = f2bf(hval);
            const unsigned short lb = f2bf(hval - bf2f(hb));
            const unsigned pk = ((unsigned)hb << 16) | ((unsigned)lb & 0xFFF0u) | tag;
            __hip_atomic_store(
                &hp_rec[(size_t)(t + 1) * (BB * HH) + (size_t)(bt * 32 + b) * HH + j0 + j_u],
                pk, __ATOMIC_RELAXED, __HIP_MEMORY_SCOPE_AGENT);
        }
        __syncthreads();   // Gs/LDS safe before next step's staging
    }
}

// ---------------------------------------------------------------------------
// Classifier split-K partial GEMM on tagged h cells (mask tag nibble)
// ---------------------------------------------------------------------------
__global__ __launch_bounds__(256) void cls_partial_kernel(
    const unsigned* __restrict__ A, const float* __restrict__ W,
    float* __restrict__ part)
{
    const int n0 = blockIdx.x * 64;
    const int s  = blockIdx.y;
    const int kbase = s * 2048;
    const int tid = threadIdx.x;
    __shared__ float As[32][68];
    __shared__ float Bs[32][68];
    const int tm = tid >> 4, tn = tid & 15;
    float acc[4][4] = {};

    for (int kt = 0; kt < 2048; kt += 32) {
        #pragma unroll
        for (int q = tid; q < 512; q += 256) {
            const int mm = q >> 3;
            const int kq = q & 7;
            uint4 v = *(const uint4*)&A[(size_t)mm * KFLAT + kbase + kt + kq * 4];
            As[kq*4+0][mm] = pk2f(v.x & 0xFFFFFFF0u); As[kq*4+1][mm] = pk2f(v.y & 0xFFFFFFF0u);
            As[kq*4+2][mm] = pk2f(v.z & 0xFFFFFFF0u); As[kq*4+3][mm] = pk2f(v.w & 0xFFFFFFF0u);
            float4 w = *(const float4*)&W[(size_t)(n0 + mm) * KFLAT + kbase + kt + kq * 4];
            Bs[kq*4+0][mm] = w.x; Bs[kq*4+1][mm] = w.y;
            Bs[kq*4+2][mm] = w.z; Bs[kq*4+3][mm] = w.w;
        }
        __syncthreads();
        #pragma unroll
        for (int k = 0; k < 32; ++k) {
            float4 a = *(const float4*)&As[k][tm * 4];
            float4 b = *(const float4*)&Bs[k][tn * 4];
            acc[0][0] += a.x*b.x; acc[0][1] += a.x*b.y; acc[0][2] += a.x*b.z; acc[0][3] += a.x*b.w;
            acc[1][0] += a.y*b.x; acc[1][1] += a.y*b.y; acc[1][2] += a.y*b.z; acc[1][3] += a.y*b.w;
            acc[2][0] += a.z*b.x; acc[2][1] += a.z*b.y; acc[2][2] += a.z*b.z; acc[2][3] += a.z*b.w;
            acc[3][0] += a.w*b.x; acc[3][1] += a.w*b.y; acc[3][2] += a.w*b.z; acc[3][3] += a.w*b.w;
        }
        __syncthreads();
    }
    #pragma unroll
    for (int i = 0; i < 4; ++i) {
        const int m = tm * 4 + i;
        #pragma unroll
        for (int j = 0; j < 4; ++j) {
            part[((size_t)s * 64 + m) * 512 + n0 + tn * 4 + j] = acc[i][j];
        }
    }
}

// ---------------------------------------------------------------------------
// Classifier finish (unchanged)
// ---------------------------------------------------------------------------
__global__ __launch_bounds__(256) void cls_final_kernel(
    const float* __restrict__ part, const float* __restrict__ b1,
    const float* __restrict__ w2, const float* __restrict__ b2,
    float* __restrict__ out)
{
    const int t = blockIdx.x;
    __shared__ float hm[512];
    for (int n = threadIdx.x; n < 512; n += 256) {
        float sacc = b1[n];
        for (int sl = 0; sl < 32; ++sl)
            sacc += part[((size_t)sl * 64 + t) * 512 + n];
        hm[n] = fmaxf(sacc, 0.f);
    }
    __syncthreads();
    if (threadIdx.x < NCC) {
        float sacc = b2[threadIdx.x];
        const float* wr = w2 + (size_t)threadIdx.x * 512;
        for (int n = 0; n < 512; ++n) sacc += hm[n] * wr[n];
        out[t * NCC + threadIdx.x] = sacc;
    }
}

// ---------------------------------------------------------------------------
extern "C" void kernel_launch(void* const* d_in, const int* in_sizes, int n_in,
                              void* d_out, int out_size, void* d_ws, size_t ws_size,
                              hipStream_t stream)
{
    const float* x     = (const float*)d_in[0];
    const float* w_ih0 = (const float*)d_in[1];
    const float* w_hh0 = (const float*)d_in[2];
    const float* b_ih0 = (const float*)d_in[3];
    const float* b_hh0 = (const float*)d_in[4];
    const float* w_ih1 = (const float*)d_in[5];
    const float* w_hh1 = (const float*)d_in[6];
    const float* b_ih1 = (const float*)d_in[7];
    const float* b_hh1 = (const float*)d_in[8];
    const float* w1    = (const float*)d_in[9];
    const float* b1    = (const float*)d_in[10];
    const float* w2    = (const float*)d_in[11];
    const float* b2    = (const float*)d_in[12];
    float* out = (float*)d_out;

    // Workspace (~102.1 MB): hpack1 region is ALIASED over xpk/w0pk (dead
    // after the layer-0 GEMM), then scrubbed with 0xFF (tag 0xF never valid).
    float*    ws     = (float*)d_ws;
    float*    xg     = ws;                                      // 64 MB
    unsigned* hpack0 = (unsigned*)(xg + (size_t)8192 * 2048);   // 17.04 MB
    unsigned* hpack1 = hpack0 + (size_t)65 * BB * HH;           // 17.04 MB (aliased)
    unsigned* xpk    = hpack1;                                  // 8 MB   (dies at GEMM)
    unsigned* w0pk   = xpk + (size_t)8192 * IND;                // 2 MB   (dies at GEMM)
    float*    part   = (float*)(hpack1 + (size_t)65 * BB * HH); // 4 MB

    // ---- pack layer-0 GEMM inputs ----
    pack_split_kernel<<<1024, 256, 0, stream>>>(x, xpk, 8192 * IND);
    pack_split_kernel<<<512,  256, 0, stream>>>(w_ih0, w0pk, GG * IND);
    hipMemsetAsync(hpack0, 0, (size_t)BB * HH * sizeof(unsigned), stream);  // h0 t=0

    // ---- layer-0 input transform ----
    gemm_pk_mfma<<<dim3(8192 / 128, GG / 128), 256, 0, stream>>>(
        xpk, w0pk, b_ih0, b_hh0, xg, IND, GG);

    // ---- scrub hpack1 (kills stale xpk/w0pk tag nibbles), zero t=0 block ----
    hipMemsetAsync(hpack1, 0xFF, (size_t)65 * BB * HH * sizeof(unsigned), stream);
    hipMemsetAsync(hpack1, 0, (size_t)BB * HH * sizeof(unsigned), stream);

    // ---- fused two-layer recurrence ----
    lstm_fused<<<256, 256, 0, stream>>>(
        xg, w_hh0, w_ih1, w_hh1, b_ih1, b_hh1, hpack0, hpack1);

    // ---- classifier (tagged h1, blocks 1..64) ----
    cls_partial_kernel<<<dim3(512 / 64, 32), 256, 0, stream>>>(
        hpack1 + (size_t)BB * HH, w1, part);
    cls_final_kernel<<<64, 256, 0, stream>>>(part, b1, w2, b2, out);
}